// Round 1
// baseline (597.284 us; speedup 1.0000x reference)
//
#include <hip/hip_runtime.h>
#include <math.h>

#define BLn 16
#define Nn 256
#define Tn 32
#define Cn 256
#define Hn 4
#define HDn 64
#define KREL 32

__device__ __forceinline__ float gelu_f(float x) {
    return 0.5f * x * (1.0f + erff(x * 0.70710678118654752440f));
}

// ---------------- sizes from corners ----------------
__global__ void k_sizes(const float* __restrict__ corners, float* __restrict__ sizes) {
    int b = blockIdx.x, n = threadIdx.x;
    const float* p = corners + (size_t)((b * Nn + n) * 8) * 3;
    float mn[3] = {1e30f, 1e30f, 1e30f}, mx[3] = {-1e30f, -1e30f, -1e30f};
    for (int v = 0; v < 8; v++)
        for (int d = 0; d < 3; d++) {
            float t = p[v * 3 + d];
            mn[d] = fminf(mn[d], t);
            mx[d] = fmaxf(mx[d], t);
        }
    for (int d = 0; d < 3; d++) sizes[(b * Nn + n) * 3 + d] = mx[d] - mn[d];
}

// ---------------- LayerNorm ----------------
__global__ void k_ln(const float* __restrict__ x, const float* __restrict__ g,
                     const float* __restrict__ be, float* __restrict__ xn) {
    int row = blockIdx.x;
    int c = threadIdx.x;
    __shared__ float red[Cn];
    float v = x[(size_t)row * Cn + c];
    red[c] = v;
    __syncthreads();
    for (int s = 128; s > 0; s >>= 1) {
        if (c < s) red[c] += red[c + s];
        __syncthreads();
    }
    float mu = red[0] * (1.0f / Cn);
    __syncthreads();
    float d = v - mu;
    red[c] = d * d;
    __syncthreads();
    for (int s = 128; s > 0; s >>= 1) {
        if (c < s) red[c] += red[c + s];
        __syncthreads();
    }
    float var = red[0] * (1.0f / Cn);
    float r = rsqrtf(var + 1e-5f);
    xn[(size_t)row * Cn + c] = d * r * g[c] + be[c];
}

// ---------------- head weights from language ----------------
__global__ void k_headw(const float* __restrict__ lang, const float* __restrict__ Wt1,
                        const float* __restrict__ bt1, const float* __restrict__ Wt2,
                        const float* __restrict__ bt2, float* __restrict__ headw) {
    int b = blockIdx.x, c = threadIdx.x;
    __shared__ float sent[Cn];
    __shared__ float t1[Cn];
    float s = 0.0f;
    for (int t = 0; t < Tn; t++) s += lang[((size_t)b * Tn + t) * Cn + c];
    sent[c] = s * (1.0f / Tn);
    __syncthreads();
    float acc = bt1[c];
    for (int i = 0; i < Cn; i++) acc += sent[i] * Wt1[i * Cn + c];
    t1[c] = gelu_f(acc);
    __syncthreads();
    if (c < Hn) {
        float a = bt2[c];
        for (int i = 0; i < Cn; i++) a += t1[i] * Wt2[i * Hn + c];
        headw[b * Hn + c] = 1.0f / (1.0f + expf(-a));
    }
}

// ---------------- KNN mask (+ obj pair mask) ----------------
__global__ void k_knn(const float* __restrict__ centers, const int* __restrict__ obj,
                      unsigned char* __restrict__ knn) {
    int bi = blockIdx.x;
    int b = bi / Nn, i = bi % Nn;
    int j = threadIdx.x;
    __shared__ float d2s[Nn];
    float cx = centers[(b * Nn + i) * 3 + 0];
    float cy = centers[(b * Nn + i) * 3 + 1];
    float cz = centers[(b * Nn + i) * 3 + 2];
    float dx = centers[(b * Nn + j) * 3 + 0] - cx;
    float dy = centers[(b * Nn + j) * 3 + 1] - cy;
    float dz = centers[(b * Nn + j) * 3 + 2] - cz;
    float dd = sqrtf(dx * dx + dy * dy + dz * dz);
    d2s[j] = dd;
    __syncthreads();
    int rank = 0;
    for (int t = 0; t < Nn; t++) {
        float o = d2s[t];
        rank += (o < dd) || (o == dd && t < j);
    }
    bool m = (rank < KREL);
    m = m && (obj[b * Nn + i] != 0) && (obj[b * Nn + j] != 0);
    knn[(size_t)bi * Nn + j] = m ? 1 : 0;
}

// ---------------- QKV projection ----------------
__global__ void k_qkv(const float* __restrict__ xn, const float* __restrict__ W,
                      const float* __restrict__ bqkv, float* __restrict__ qb,
                      float* __restrict__ kb, float* __restrict__ vb) {
    int row = blockIdx.x;  // b*N + n
    int tid = threadIdx.x;
    __shared__ float xr[Cn];
    xr[tid] = xn[(size_t)row * Cn + tid];
    __syncthreads();
    int b = row / Nn, n = row % Nn;
    for (int s = 0; s < 3; s++) {
        int o = s * Cn + tid;
        float acc = bqkv[o];
        for (int i = 0; i < Cn; i++) acc += xr[i] * W[(size_t)i * (3 * Cn) + o];
        int h = tid / HDn, hd = tid % HDn;
        float* dst = (s == 0) ? qb : ((s == 1) ? kb : vb);
        dst[(((size_t)b * Hn + h) * Nn + n) * HDn + hd] = acc;
    }
}

// ---------------- pairwise geometry bias MLP (the heavy kernel) ----------------
__global__ void __launch_bounds__(256) k_geombias(
    const float* __restrict__ centers, const float* __restrict__ sizes,
    const float* __restrict__ Wg1, const float* __restrict__ bg1,
    const float* __restrict__ Wg2, const float* __restrict__ bg2,
    const float* __restrict__ headw, const float* __restrict__ alphap,
    float* __restrict__ bias_eff) {
    __shared__ float w1[12][Cn];
    __shared__ float b1[Cn];
    __shared__ float w2[Cn][Hn];
    int bi = blockIdx.x;
    int b = bi / Nn, i = bi % Nn;
    int j = threadIdx.x;
    for (int g = 0; g < 12; g++) w1[g][j] = Wg1[g * Cn + j];
    b1[j] = bg1[j];
    for (int h = 0; h < Hn; h++) w2[j][h] = Wg2[j * Hn + h];
    __syncthreads();

    float ci[3], cj[3], si[3], sj[3];
    for (int d = 0; d < 3; d++) {
        ci[d] = centers[(b * Nn + i) * 3 + d];
        cj[d] = centers[(b * Nn + j) * 3 + d];
        si[d] = sizes[(b * Nn + i) * 3 + d];
        sj[d] = sizes[(b * Nn + j) * 3 + d];
    }
    float rx = cj[0] - ci[0], ry = cj[1] - ci[1], rz = cj[2] - ci[2];
    float dist = sqrtf(rx * rx + ry * ry + rz * rz);
    float horiz = sqrtf(rx * rx + ry * ry);
    float geom[12];
    geom[0] = rx; geom[1] = ry; geom[2] = rz;
    geom[3] = dist; geom[4] = horiz;
    geom[5] = rz / (dist + 1e-6f);
    for (int d = 0; d < 3; d++) {
        geom[6 + d] = sj[d] - si[d];
        geom[9 + d] = sj[d] / (si[d] + 1e-6f);
    }
    float acc[Hn] = {0.f, 0.f, 0.f, 0.f};
    for (int c = 0; c < Cn; c++) {
        float t = b1[c];
#pragma unroll
        for (int g = 0; g < 12; g++) t += geom[g] * w1[g][c];
        t = gelu_f(t);
#pragma unroll
        for (int h = 0; h < Hn; h++) acc[h] += t * w2[c][h];
    }
    float alpha = alphap[0];
    for (int h = 0; h < Hn; h++) {
        float beff = alpha * headw[b * Hn + h] * (acc[h] + bg2[h]);
        bias_eff[((((size_t)b * Hn + h) * Nn) + i) * Nn + j] = beff;
    }
}

// ---------------- attention ----------------
__global__ void k_attn(const float* __restrict__ qb, const float* __restrict__ kb,
                       const float* __restrict__ vb, const float* __restrict__ bias_eff,
                       const unsigned char* __restrict__ knn, float* __restrict__ attn_out,
                       float* __restrict__ hout) {
    int blk = blockIdx.x;  // (b*H + h)*N + i
    int i = blk % Nn;
    int bh = blk / Nn;
    int b = bh / Hn, h = bh % Hn;
    int j = threadIdx.x;
    __shared__ float q[HDn];
    __shared__ float red[Nn];
    __shared__ float arow[Nn];
    if (j < HDn) q[j] = qb[((size_t)bh * Nn + i) * HDn + j];
    __syncthreads();
    const float* krow = kb + ((size_t)bh * Nn + j) * HDn;
    float acc = 0.0f;
    for (int d = 0; d < HDn; d++) acc += q[d] * krow[d];
    float logit = acc * 0.125f + bias_eff[((size_t)bh * Nn + i) * Nn + j];
    bool m = knn[((size_t)(b * Nn + i)) * Nn + j] != 0;
    logit = m ? logit : -1e9f;
    red[j] = logit;
    __syncthreads();
    for (int s = 128; s > 0; s >>= 1) {
        if (j < s) red[j] = fmaxf(red[j], red[j + s]);
        __syncthreads();
    }
    float mx = red[0];
    __syncthreads();
    float e = expf(logit - mx);
    red[j] = e;
    __syncthreads();
    for (int s = 128; s > 0; s >>= 1) {
        if (j < s) red[j] += red[j + s];
        __syncthreads();
    }
    float sum = red[0];
    float a = e / sum;
    attn_out[((size_t)bh * Nn + i) * Nn + j] = a;
    arow[j] = a;
    __syncthreads();
    if (j < HDn) {
        float o = 0.0f;
        for (int t = 0; t < Nn; t++) o += arow[t] * vb[((size_t)bh * Nn + t) * HDn + j];
        hout[((size_t)(b * Nn + i)) * Cn + h * HDn + j] = o;
    }
}

// ---------------- output projection + residual ----------------
__global__ void k_proj(const float* __restrict__ hout, const float* __restrict__ Wp,
                       const float* __restrict__ bp, const float* __restrict__ x,
                       float* __restrict__ xout) {
    int row = blockIdx.x;
    int c = threadIdx.x;
    __shared__ float hr[Cn];
    hr[c] = hout[(size_t)row * Cn + c];
    __syncthreads();
    float acc = bp[c];
    for (int i = 0; i < Cn; i++) acc += hr[i] * Wp[i * Cn + c];
    xout[(size_t)row * Cn + c] = x[(size_t)row * Cn + c] + acc;
}

extern "C" void kernel_launch(void* const* d_in, const int* in_sizes, int n_in,
                              void* d_out, int out_size, void* d_ws, size_t ws_size,
                              hipStream_t stream) {
    const float* x       = (const float*)d_in[0];
    const float* lang    = (const float*)d_in[1];
    const float* centers = (const float*)d_in[2];
    const float* corners = (const float*)d_in[3];
    const int*   obj     = (const int*)d_in[4];
    const float* ln_g    = (const float*)d_in[5];
    const float* ln_b    = (const float*)d_in[6];
    const float* W_qkv   = (const float*)d_in[7];
    const float* b_qkv   = (const float*)d_in[8];
    const float* W_proj  = (const float*)d_in[9];
    const float* b_proj  = (const float*)d_in[10];
    const float* Wg1     = (const float*)d_in[11];
    const float* bg1     = (const float*)d_in[12];
    const float* Wg2     = (const float*)d_in[13];
    const float* bg2     = (const float*)d_in[14];
    const float* Wt1     = (const float*)d_in[15];
    const float* bt1     = (const float*)d_in[16];
    const float* Wt2     = (const float*)d_in[17];
    const float* bt2     = (const float*)d_in[18];
    const float* alpha   = (const float*)d_in[19];

    float* out = (float*)d_out;
    float* xout     = out;                 // BL*N*C        = 1048576
    float* attn     = out + 1048576;       // BL*H*N*N      = 4194304
    float* bias_eff = out + 5242880;       // BL*H*N*N      = 4194304

    float* ws   = (float*)d_ws;
    float* xn    = ws;                 // 1048576
    float* qb    = xn + 1048576;       // 1048576
    float* kb    = qb + 1048576;       // 1048576
    float* vb    = kb + 1048576;       // 1048576
    float* hout  = vb + 1048576;       // 1048576
    float* sizes = hout + 1048576;     // 12288
    float* headw = sizes + 12288;      // 64
    unsigned char* knn = (unsigned char*)(headw + 64);  // 1 MiB

    k_sizes<<<BLn, Nn, 0, stream>>>(corners, sizes);
    k_ln<<<BLn * Nn, Cn, 0, stream>>>(x, ln_g, ln_b, xn);
    k_headw<<<BLn, Cn, 0, stream>>>(lang, Wt1, bt1, Wt2, bt2, headw);
    k_knn<<<BLn * Nn, Nn, 0, stream>>>(centers, obj, knn);
    k_qkv<<<BLn * Nn, Cn, 0, stream>>>(xn, W_qkv, b_qkv, qb, kb, vb);
    k_geombias<<<BLn * Nn, Nn, 0, stream>>>(centers, sizes, Wg1, bg1, Wg2, bg2, headw, alpha,
                                            bias_eff);
    k_attn<<<BLn * Hn * Nn, Nn, 0, stream>>>(qb, kb, vb, bias_eff, knn, attn, hout);
    k_proj<<<BLn * Nn, Cn, 0, stream>>>(hout, W_proj, b_proj, x, xout);
}

// Round 2
// 319.871 us; speedup vs baseline: 1.8673x; 1.8673x over previous
//
#include <hip/hip_runtime.h>
#include <math.h>

#define BLn 16
#define Nn 256
#define Tn 32
#define Cn 256
#define Hn 4
#define HDn 64
#define KREL 32

__device__ __forceinline__ float gelu_exact(float x) {
    return 0.5f * x * (1.0f + erff(x * 0.70710678118654752440f));
}

// tanh-form gelu via hardware exp2/rcp: max |dev| vs exact ~3e-4, amplified to
// <1e-4 on bias_eff (weights ~N(0,0.02), alpha=0.05) -- far below threshold.
__device__ __forceinline__ float gelu_fast(float x) {
    float x2 = x * x;
    float inner = fmaf(0.07135481f, x2, 1.59576912f);  // 2*sqrt(2/pi)*(1+0.044715 x^2)
    float u = x * inner;
    float e = __builtin_amdgcn_exp2f(-1.44269504f * u);
    return x * __builtin_amdgcn_rcpf(1.0f + e);
}

// ---------------- sizes from corners ----------------
__global__ void k_sizes(const float* __restrict__ corners, float* __restrict__ sizes) {
    int b = blockIdx.x, n = threadIdx.x;
    const float* p = corners + (size_t)((b * Nn + n) * 8) * 3;
    float mn[3] = {1e30f, 1e30f, 1e30f}, mx[3] = {-1e30f, -1e30f, -1e30f};
    for (int v = 0; v < 8; v++)
        for (int d = 0; d < 3; d++) {
            float t = p[v * 3 + d];
            mn[d] = fminf(mn[d], t);
            mx[d] = fmaxf(mx[d], t);
        }
    for (int d = 0; d < 3; d++) sizes[(b * Nn + n) * 3 + d] = mx[d] - mn[d];
}

// ---------------- LayerNorm (single pass, shfl reduce) ----------------
__global__ void k_ln(const float* __restrict__ x, const float* __restrict__ g,
                     const float* __restrict__ be, float* __restrict__ xn) {
    int row = blockIdx.x;
    int c = threadIdx.x;
    float v = x[(size_t)row * Cn + c];
    float s = v, q = v * v;
    for (int m = 32; m > 0; m >>= 1) {
        s += __shfl_xor(s, m, 64);
        q += __shfl_xor(q, m, 64);
    }
    __shared__ float ss[4], qq[4];
    int w = c >> 6, l = c & 63;
    if (l == 0) { ss[w] = s; qq[w] = q; }
    __syncthreads();
    s = ss[0] + ss[1] + ss[2] + ss[3];
    q = qq[0] + qq[1] + qq[2] + qq[3];
    float mu = s * (1.0f / Cn);
    float var = q * (1.0f / Cn) - mu * mu;
    float r = rsqrtf(var + 1e-5f);
    xn[(size_t)row * Cn + c] = (v - mu) * r * g[c] + be[c];
}

// ---------------- head weights from language ----------------
__global__ void k_headw(const float* __restrict__ lang, const float* __restrict__ Wt1,
                        const float* __restrict__ bt1, const float* __restrict__ Wt2,
                        const float* __restrict__ bt2, float* __restrict__ headw) {
    int b = blockIdx.x, c = threadIdx.x;
    __shared__ float sent[Cn];
    __shared__ float t1[Cn];
    float s = 0.0f;
    for (int t = 0; t < Tn; t++) s += lang[((size_t)b * Tn + t) * Cn + c];
    sent[c] = s * (1.0f / Tn);
    __syncthreads();
    float acc = bt1[c];
    for (int i = 0; i < Cn; i++) acc += sent[i] * Wt1[i * Cn + c];
    t1[c] = gelu_exact(acc);
    __syncthreads();
    if (c < Hn) {
        float a = bt2[c];
        for (int i = 0; i < Cn; i++) a += t1[i] * Wt2[i * Hn + c];
        headw[b * Hn + c] = 1.0f / (1.0f + expf(-a));
    }
}

// ---------------- KNN mask (+ obj pair mask), unchanged (passed) ----------------
__global__ void k_knn(const float* __restrict__ centers, const int* __restrict__ obj,
                      unsigned char* __restrict__ knn) {
    int bi = blockIdx.x;
    int b = bi / Nn, i = bi % Nn;
    int j = threadIdx.x;
    __shared__ float d2s[Nn];
    float cx = centers[(b * Nn + i) * 3 + 0];
    float cy = centers[(b * Nn + i) * 3 + 1];
    float cz = centers[(b * Nn + i) * 3 + 2];
    float dx = centers[(b * Nn + j) * 3 + 0] - cx;
    float dy = centers[(b * Nn + j) * 3 + 1] - cy;
    float dz = centers[(b * Nn + j) * 3 + 2] - cz;
    float dd = sqrtf(dx * dx + dy * dy + dz * dz);
    d2s[j] = dd;
    __syncthreads();
    int rank = 0;
    for (int t = 0; t < Nn; t++) {
        float o = d2s[t];
        rank += (o < dd) || (o == dd && t < j);
    }
    bool m = (rank < KREL);
    m = m && (obj[b * Nn + i] != 0) && (obj[b * Nn + j] != 0);
    knn[(size_t)bi * Nn + j] = m ? 1 : 0;
}

// ---------------- separable part of geom MLP: P(b,n,c), stored c-major ----------------
__global__ void k_geoprep(const float* __restrict__ centers, const float* __restrict__ sizes,
                          const float* __restrict__ Wg1, float* __restrict__ P_T) {
    int blk = blockIdx.x;
    int b = blk >> 8, c = blk & 255;
    int n = threadIdx.x;
    float c0 = centers[(b * Nn + n) * 3 + 0];
    float c1 = centers[(b * Nn + n) * 3 + 1];
    float c2 = centers[(b * Nn + n) * 3 + 2];
    float s0 = sizes[(b * Nn + n) * 3 + 0];
    float s1 = sizes[(b * Nn + n) * 3 + 1];
    float s2 = sizes[(b * Nn + n) * 3 + 2];
    float p = c0 * Wg1[0 * Cn + c] + c1 * Wg1[1 * Cn + c] + c2 * Wg1[2 * Cn + c] +
              s0 * Wg1[6 * Cn + c] + s1 * Wg1[7 * Cn + c] + s2 * Wg1[8 * Cn + c];
    P_T[((size_t)b * Cn + c) * Nn + n] = p;
}

// ---------------- pairwise geometry bias MLP ----------------
__global__ void __launch_bounds__(256) k_geombias(
    const float* __restrict__ centers, const float* __restrict__ sizes,
    const float* __restrict__ Wg1, const float* __restrict__ bg1,
    const float* __restrict__ Wg2, const float* __restrict__ bg2,
    const float* __restrict__ headw, const float* __restrict__ alphap,
    const float* __restrict__ P_T, float* __restrict__ bias_eff) {
    __shared__ float U[Cn][8];     // {w3,w4,w5,w9,w10,w11, b1 - P_i, pad}
    __shared__ float4 W2[Cn];
    int bi = blockIdx.x;
    int b = bi >> 8, i = bi & 255;
    int tid = threadIdx.x;

    float ci0 = centers[(b * Nn + i) * 3 + 0];
    float ci1 = centers[(b * Nn + i) * 3 + 1];
    float ci2 = centers[(b * Nn + i) * 3 + 2];
    float si0 = sizes[(b * Nn + i) * 3 + 0];
    float si1 = sizes[(b * Nn + i) * 3 + 1];
    float si2 = sizes[(b * Nn + i) * 3 + 2];
    {
        int c = tid;
        float pi = ci0 * Wg1[0 * Cn + c] + ci1 * Wg1[1 * Cn + c] + ci2 * Wg1[2 * Cn + c] +
                   si0 * Wg1[6 * Cn + c] + si1 * Wg1[7 * Cn + c] + si2 * Wg1[8 * Cn + c];
        U[c][0] = Wg1[3 * Cn + c];
        U[c][1] = Wg1[4 * Cn + c];
        U[c][2] = Wg1[5 * Cn + c];
        U[c][3] = Wg1[9 * Cn + c];
        U[c][4] = Wg1[10 * Cn + c];
        U[c][5] = Wg1[11 * Cn + c];
        U[c][6] = bg1[c] - pi;
        W2[c] = *(const float4*)(Wg2 + c * Hn);
    }
    __syncthreads();

    int j = tid;
    float cj0 = centers[(b * Nn + j) * 3 + 0];
    float cj1 = centers[(b * Nn + j) * 3 + 1];
    float cj2 = centers[(b * Nn + j) * 3 + 2];
    float sj0 = sizes[(b * Nn + j) * 3 + 0];
    float sj1 = sizes[(b * Nn + j) * 3 + 1];
    float sj2 = sizes[(b * Nn + j) * 3 + 2];
    float rx = cj0 - ci0, ry = cj1 - ci1, rz = cj2 - ci2;
    float h2 = rx * rx + ry * ry;
    float d2 = h2 + rz * rz;
    float dist = sqrtf(d2), horiz = sqrtf(h2);
    float ce = rz / (dist + 1e-6f);
    float r0 = sj0 / (si0 + 1e-6f);
    float r1 = sj1 / (si1 + 1e-6f);
    float r2 = sj2 / (si2 + 1e-6f);

    const float* pT = P_T + (size_t)b * Cn * Nn + j;
    float a0 = 0.f, a1 = 0.f, a2 = 0.f, a3 = 0.f;
#pragma unroll 4
    for (int c = 0; c < Cn; c++) {
        float pj = pT[(size_t)c * Nn];
        float4 u0 = *(const float4*)&U[c][0];
        float4 u1 = *(const float4*)&U[c][4];
        float t = u1.z + pj;
        t = fmaf(dist, u0.x, t);
        t = fmaf(horiz, u0.y, t);
        t = fmaf(ce, u0.z, t);
        t = fmaf(r0, u0.w, t);
        t = fmaf(r1, u1.x, t);
        t = fmaf(r2, u1.y, t);
        float g = gelu_fast(t);
        float4 w2 = W2[c];
        a0 = fmaf(g, w2.x, a0);
        a1 = fmaf(g, w2.y, a1);
        a2 = fmaf(g, w2.z, a2);
        a3 = fmaf(g, w2.w, a3);
    }
    float alpha = alphap[0];
    size_t NN = (size_t)Nn * Nn;
    size_t base = ((size_t)(b * Hn) * Nn + i) * Nn + j;
    bias_eff[base + 0 * NN] = alpha * headw[b * Hn + 0] * (a0 + bg2[0]);
    bias_eff[base + 1 * NN] = alpha * headw[b * Hn + 1] * (a1 + bg2[1]);
    bias_eff[base + 2 * NN] = alpha * headw[b * Hn + 2] * (a2 + bg2[2]);
    bias_eff[base + 3 * NN] = alpha * headw[b * Hn + 3] * (a3 + bg2[3]);
}

// ---------------- QKV projection, 8 rows per block ----------------
__global__ void __launch_bounds__(256) k_qkv(const float* __restrict__ xn,
                                             const float* __restrict__ W,
                                             const float* __restrict__ bqkv,
                                             float* __restrict__ qb, float* __restrict__ kb,
                                             float* __restrict__ vb) {
    __shared__ float xrT[Cn][8];
    int r0 = blockIdx.x * 8;
    int tid = threadIdx.x;
    for (int r = 0; r < 8; r++) xrT[tid][r] = xn[(size_t)(r0 + r) * Cn + tid];
    __syncthreads();
    for (int s = 0; s < 3; s++) {
        int o = s * Cn + tid;
        float bias = bqkv[o];
        float acc[8];
#pragma unroll
        for (int r = 0; r < 8; r++) acc[r] = bias;
        for (int i2 = 0; i2 < Cn; i2++) {
            float w = W[(size_t)i2 * (3 * Cn) + o];
            float4 x0 = *(const float4*)&xrT[i2][0];
            float4 x1 = *(const float4*)&xrT[i2][4];
            acc[0] = fmaf(x0.x, w, acc[0]);
            acc[1] = fmaf(x0.y, w, acc[1]);
            acc[2] = fmaf(x0.z, w, acc[2]);
            acc[3] = fmaf(x0.w, w, acc[3]);
            acc[4] = fmaf(x1.x, w, acc[4]);
            acc[5] = fmaf(x1.y, w, acc[5]);
            acc[6] = fmaf(x1.z, w, acc[6]);
            acc[7] = fmaf(x1.w, w, acc[7]);
        }
        float* dst = (s == 0) ? qb : ((s == 1) ? kb : vb);
        int hh = tid >> 6, hd = tid & 63;
#pragma unroll
        for (int r = 0; r < 8; r++) {
            int row = r0 + r;
            int bb = row >> 8, n = row & 255;
            dst[(((size_t)bb * Hn + hh) * Nn + n) * HDn + hd] = acc[r];
        }
    }
}

// ---------------- attention: 32 query rows per block ----------------
__global__ void __launch_bounds__(256) k_attn(const float* __restrict__ qb,
                                              const float* __restrict__ kb,
                                              const float* __restrict__ vb,
                                              const float* __restrict__ bias_eff,
                                              const unsigned char* __restrict__ knn,
                                              float* __restrict__ attn_out,
                                              float* __restrict__ hout) {
    __shared__ float qs[32][HDn];
    __shared__ float L[32][Nn];
    int blk = blockIdx.x;
    int bh = blk >> 3, it = blk & 7;
    int i0 = it * 32;
    int b = bh >> 2, h = bh & 3;
    int tid = threadIdx.x;

    for (int r = 0; r < 8; r++) {
        int idx = r * 256 + tid;
        int ii = idx >> 6, d = idx & 63;
        qs[ii][d] = qb[((size_t)bh * Nn + i0 + ii) * HDn + d];
    }
    float kr[HDn];
    {
        const float4* kp = (const float4*)(kb + ((size_t)bh * Nn + tid) * HDn);
#pragma unroll
        for (int d4 = 0; d4 < 16; d4++) {
            float4 t = kp[d4];
            kr[d4 * 4 + 0] = t.x;
            kr[d4 * 4 + 1] = t.y;
            kr[d4 * 4 + 2] = t.z;
            kr[d4 * 4 + 3] = t.w;
        }
    }
    __syncthreads();

    int j = tid;
    for (int ii = 0; ii < 32; ii++) {
        float acc = 0.0f;
#pragma unroll
        for (int d4 = 0; d4 < 16; d4++) {
            float4 qv = *(const float4*)&qs[ii][d4 * 4];
            acc = fmaf(qv.x, kr[d4 * 4 + 0], acc);
            acc = fmaf(qv.y, kr[d4 * 4 + 1], acc);
            acc = fmaf(qv.z, kr[d4 * 4 + 2], acc);
            acc = fmaf(qv.w, kr[d4 * 4 + 3], acc);
        }
        int ig = i0 + ii;
        float lg = fmaf(acc, 0.125f, bias_eff[((size_t)bh * Nn + ig) * Nn + j]);
        bool m = knn[((size_t)(b * Nn + ig)) * Nn + j] != 0;
        L[ii][j] = m ? lg : -1e9f;
    }
    __syncthreads();

    // softmax: 8 lanes per row
    int r = tid >> 3, kk = tid & 7;
    float mx = -1e30f;
    for (int m8 = 0; m8 < 32; m8++) mx = fmaxf(mx, L[r][kk + 8 * m8]);
    mx = fmaxf(mx, __shfl_xor(mx, 1, 64));
    mx = fmaxf(mx, __shfl_xor(mx, 2, 64));
    mx = fmaxf(mx, __shfl_xor(mx, 4, 64));
    float s = 0.0f;
    for (int m8 = 0; m8 < 32; m8++) {
        float e = __builtin_amdgcn_exp2f((L[r][kk + 8 * m8] - mx) * 1.44269504f);
        s += e;
        L[r][kk + 8 * m8] = e;
    }
    s += __shfl_xor(s, 1, 64);
    s += __shfl_xor(s, 2, 64);
    s += __shfl_xor(s, 4, 64);
    float inv = 1.0f / s;
    for (int m8 = 0; m8 < 32; m8++) {
        float a = L[r][kk + 8 * m8] * inv;
        L[r][kk + 8 * m8] = a;
        attn_out[((size_t)bh * Nn + i0 + r) * Nn + kk + 8 * m8] = a;
    }
    __syncthreads();

    // PV: wave w handles rows {w, w+4, ..., w+28}, lane d = output dim
    int w = tid >> 6, d = tid & 63;
    float acc8[8] = {0.f, 0.f, 0.f, 0.f, 0.f, 0.f, 0.f, 0.f};
    for (int t4 = 0; t4 < 64; t4++) {
        int t = t4 * 4;
        float v0 = vb[((size_t)bh * Nn + t + 0) * HDn + d];
        float v1 = vb[((size_t)bh * Nn + t + 1) * HDn + d];
        float v2 = vb[((size_t)bh * Nn + t + 2) * HDn + d];
        float v3 = vb[((size_t)bh * Nn + t + 3) * HDn + d];
#pragma unroll
        for (int k8 = 0; k8 < 8; k8++) {
            float4 a4 = *(const float4*)&L[w + 4 * k8][t];
            acc8[k8] = fmaf(a4.x, v0, fmaf(a4.y, v1, fmaf(a4.z, v2, fmaf(a4.w, v3, acc8[k8]))));
        }
    }
#pragma unroll
    for (int k8 = 0; k8 < 8; k8++) {
        int ig = i0 + w + 4 * k8;
        hout[((size_t)(b * Nn + ig)) * Cn + h * HDn + d] = acc8[k8];
    }
}

// ---------------- output projection + residual, 8 rows per block ----------------
__global__ void __launch_bounds__(256) k_proj(const float* __restrict__ hout,
                                              const float* __restrict__ Wp,
                                              const float* __restrict__ bp,
                                              const float* __restrict__ x,
                                              float* __restrict__ xout) {
    __shared__ float hrT[Cn][8];
    int r0 = blockIdx.x * 8;
    int tid = threadIdx.x;
    for (int r = 0; r < 8; r++) hrT[tid][r] = hout[(size_t)(r0 + r) * Cn + tid];
    __syncthreads();
    float acc[8];
    float bias = bp[tid];
#pragma unroll
    for (int r = 0; r < 8; r++) acc[r] = bias;
    for (int i2 = 0; i2 < Cn; i2++) {
        float w = Wp[(size_t)i2 * Cn + tid];
        float4 x0 = *(const float4*)&hrT[i2][0];
        float4 x1 = *(const float4*)&hrT[i2][4];
        acc[0] = fmaf(x0.x, w, acc[0]);
        acc[1] = fmaf(x0.y, w, acc[1]);
        acc[2] = fmaf(x0.z, w, acc[2]);
        acc[3] = fmaf(x0.w, w, acc[3]);
        acc[4] = fmaf(x1.x, w, acc[4]);
        acc[5] = fmaf(x1.y, w, acc[5]);
        acc[6] = fmaf(x1.z, w, acc[6]);
        acc[7] = fmaf(x1.w, w, acc[7]);
    }
#pragma unroll
    for (int r = 0; r < 8; r++) {
        size_t idx = (size_t)(r0 + r) * Cn + tid;
        xout[idx] = x[idx] + acc[r];
    }
}

extern "C" void kernel_launch(void* const* d_in, const int* in_sizes, int n_in,
                              void* d_out, int out_size, void* d_ws, size_t ws_size,
                              hipStream_t stream) {
    const float* x       = (const float*)d_in[0];
    const float* lang    = (const float*)d_in[1];
    const float* centers = (const float*)d_in[2];
    const float* corners = (const float*)d_in[3];
    const int*   obj     = (const int*)d_in[4];
    const float* ln_g    = (const float*)d_in[5];
    const float* ln_b    = (const float*)d_in[6];
    const float* W_qkv   = (const float*)d_in[7];
    const float* b_qkv   = (const float*)d_in[8];
    const float* W_proj  = (const float*)d_in[9];
    const float* b_proj  = (const float*)d_in[10];
    const float* Wg1     = (const float*)d_in[11];
    const float* bg1     = (const float*)d_in[12];
    const float* Wg2     = (const float*)d_in[13];
    const float* bg2     = (const float*)d_in[14];
    const float* Wt1     = (const float*)d_in[15];
    const float* bt1     = (const float*)d_in[16];
    const float* Wt2     = (const float*)d_in[17];
    const float* bt2     = (const float*)d_in[18];
    const float* alpha   = (const float*)d_in[19];

    float* out = (float*)d_out;
    float* xout     = out;                 // BL*N*C
    float* attn     = out + 1048576;       // BL*H*N*N
    float* bias_eff = out + 5242880;       // BL*H*N*N

    float* ws = (float*)d_ws;
    float* xn      = ws;                  // 1048576
    float* qb      = xn + 1048576;        // 1048576
    float* kb      = qb + 1048576;        // 1048576
    float* vb      = kb + 1048576;        // 1048576
    float* PT_hout = vb + 1048576;        // 1048576  (P_T then reused as hout)
    float* sizes   = PT_hout + 1048576;   // 12288
    float* headw   = sizes + 12288;       // 64
    unsigned char* knn = (unsigned char*)(headw + 64);  // 1 MiB

    k_sizes<<<BLn, Nn, 0, stream>>>(corners, sizes);
    k_ln<<<BLn * Nn, Cn, 0, stream>>>(x, ln_g, ln_b, xn);
    k_headw<<<BLn, Cn, 0, stream>>>(lang, Wt1, bt1, Wt2, bt2, headw);
    k_knn<<<BLn * Nn, Nn, 0, stream>>>(centers, obj, knn);
    k_geoprep<<<BLn * Cn, Nn, 0, stream>>>(centers, sizes, Wg1, PT_hout);
    k_qkv<<<BLn * Nn / 8, Cn, 0, stream>>>(xn, W_qkv, b_qkv, qb, kb, vb);
    k_geombias<<<BLn * Nn, Nn, 0, stream>>>(centers, sizes, Wg1, bg1, Wg2, bg2, headw, alpha,
                                            PT_hout, bias_eff);
    k_attn<<<BLn * Hn * Nn / 32, Nn, 0, stream>>>(qb, kb, vb, bias_eff, knn, attn, PT_hout);
    k_proj<<<BLn * Nn / 8, Cn, 0, stream>>>(PT_hout, W_proj, b_proj, x, xout);
}

// Round 3
// 265.408 us; speedup vs baseline: 2.2504x; 1.2052x over previous
//
#include <hip/hip_runtime.h>
#include <math.h>

#define BLn 16
#define Nn 256
#define Tn 32
#define Cn 256
#define Hn 4
#define HDn 64
#define KREL 32

typedef float f32x4 __attribute__((ext_vector_type(4)));
typedef __bf16 bf16x8 __attribute__((ext_vector_type(8)));

__device__ __forceinline__ float gelu_exact(float x) {
    return 0.5f * x * (1.0f + erff(x * 0.70710678118654752440f));
}

// tanh-form gelu via hardware exp2/rcp: max |dev| vs exact ~3e-4 (validated r2).
__device__ __forceinline__ float gelu_fast(float x) {
    float x2 = x * x;
    float inner = fmaf(0.07135481f, x2, 1.59576912f);
    float u = x * inner;
    float e = __builtin_amdgcn_exp2f(-1.44269504f * u);
    return x * __builtin_amdgcn_rcpf(1.0f + e);
}

// ---------------- sizes from corners ----------------
__global__ void k_sizes(const float* __restrict__ corners, float* __restrict__ sizes) {
    int b = blockIdx.x, n = threadIdx.x;
    const float* p = corners + (size_t)((b * Nn + n) * 8) * 3;
    float mn[3] = {1e30f, 1e30f, 1e30f}, mx[3] = {-1e30f, -1e30f, -1e30f};
    for (int v = 0; v < 8; v++)
        for (int d = 0; d < 3; d++) {
            float t = p[v * 3 + d];
            mn[d] = fminf(mn[d], t);
            mx[d] = fmaxf(mx[d], t);
        }
    for (int d = 0; d < 3; d++) sizes[(b * Nn + n) * 3 + d] = mx[d] - mn[d];
}

// ---------------- LayerNorm ----------------
__global__ void k_ln(const float* __restrict__ x, const float* __restrict__ g,
                     const float* __restrict__ be, float* __restrict__ xn) {
    int row = blockIdx.x;
    int c = threadIdx.x;
    float v = x[(size_t)row * Cn + c];
    float s = v, q = v * v;
    for (int m = 32; m > 0; m >>= 1) {
        s += __shfl_xor(s, m, 64);
        q += __shfl_xor(q, m, 64);
    }
    __shared__ float ss[4], qq[4];
    int w = c >> 6, l = c & 63;
    if (l == 0) { ss[w] = s; qq[w] = q; }
    __syncthreads();
    s = ss[0] + ss[1] + ss[2] + ss[3];
    q = qq[0] + qq[1] + qq[2] + qq[3];
    float mu = s * (1.0f / Cn);
    float var = q * (1.0f / Cn) - mu * mu;
    float r = rsqrtf(var + 1e-5f);
    xn[(size_t)row * Cn + c] = (v - mu) * r * g[c] + be[c];
}

// ---------------- head weights from language ----------------
__global__ void k_headw(const float* __restrict__ lang, const float* __restrict__ Wt1,
                        const float* __restrict__ bt1, const float* __restrict__ Wt2,
                        const float* __restrict__ bt2, float* __restrict__ headw) {
    int b = blockIdx.x, c = threadIdx.x;
    __shared__ float sent[Cn];
    __shared__ float t1[Cn];
    float s = 0.0f;
    for (int t = 0; t < Tn; t++) s += lang[((size_t)b * Tn + t) * Cn + c];
    sent[c] = s * (1.0f / Tn);
    __syncthreads();
    float acc = bt1[c];
    for (int i = 0; i < Cn; i++) acc += sent[i] * Wt1[i * Cn + c];
    t1[c] = gelu_exact(acc);
    __syncthreads();
    if (c < Hn) {
        float a = bt2[c];
        for (int i = 0; i < Cn; i++) a += t1[i] * Wt2[i * Hn + c];
        headw[b * Hn + c] = 1.0f / (1.0f + expf(-a));
    }
}

// ---------------- KNN mask (+ obj pair mask) ----------------
__global__ void k_knn(const float* __restrict__ centers, const int* __restrict__ obj,
                      unsigned char* __restrict__ knn) {
    int bi = blockIdx.x;
    int b = bi / Nn, i = bi % Nn;
    int j = threadIdx.x;
    __shared__ float d2s[Nn];
    float cx = centers[(b * Nn + i) * 3 + 0];
    float cy = centers[(b * Nn + i) * 3 + 1];
    float cz = centers[(b * Nn + i) * 3 + 2];
    float dx = centers[(b * Nn + j) * 3 + 0] - cx;
    float dy = centers[(b * Nn + j) * 3 + 1] - cy;
    float dz = centers[(b * Nn + j) * 3 + 2] - cz;
    float dd = sqrtf(dx * dx + dy * dy + dz * dz);
    d2s[j] = dd;
    __syncthreads();
    int rank = 0;
    for (int t = 0; t < Nn; t++) {
        float o = d2s[t];
        rank += (o < dd) || (o == dd && t < j);
    }
    bool m = (rank < KREL);
    m = m && (obj[b * Nn + i] != 0) && (obj[b * Nn + j] != 0);
    knn[(size_t)bi * Nn + j] = m ? 1 : 0;
}

// ---------------- pairwise geometry bias MLP, MFMA version ----------------
// Layer1: [256 j x K=32(13 real feats incl 1.0-bias row)] @ W1 -> t[j][c], gelu on VALU,
// Layer2: g[j][c] @ W2[256 c x 16(4 real h)] accumulated over 8 c-chunks of 32.
__global__ void __launch_bounds__(256) k_geombias(
    const float* __restrict__ centers, const float* __restrict__ sizes,
    const float* __restrict__ Wg1, const float* __restrict__ bg1,
    const float* __restrict__ Wg2, const float* __restrict__ bg2,
    const float* __restrict__ headw, const float* __restrict__ alphap,
    float* __restrict__ bias_eff) {
    __shared__ __bf16 fT[Nn][24];    // [j][k]  A-frag layout, k>=13 zero  (12.0 KB)
    __shared__ __bf16 W1T[Cn][24];   // [c][k]  B-frag layout              (12.0 KB)
    __shared__ __bf16 W2T[16][264];  // [h][c]  B-frag layout, h>=4 zero   ( 8.25 KB)
    __shared__ __bf16 gbuf[4][64][40];  // per-wave g tile [j][c-chunk]    (20.0 KB)

    int bi = blockIdx.x;
    int b = bi >> 8, i = bi & 255;
    int tid = threadIdx.x;

    // ---- stage weights (thread = c) ----
    {
        int c = tid;
        __bf16 t1[24];
#pragma unroll
        for (int k = 0; k < 12; k++) t1[k] = (__bf16)Wg1[k * Cn + c];
        t1[12] = (__bf16)bg1[c];
#pragma unroll
        for (int k = 13; k < 24; k++) t1[k] = (__bf16)0.f;
        *(bf16x8*)&W1T[c][0] = *(bf16x8*)&t1[0];
        *(bf16x8*)&W1T[c][8] = *(bf16x8*)&t1[8];
        *(bf16x8*)&W1T[c][16] = *(bf16x8*)&t1[16];
#pragma unroll
        for (int h = 0; h < 16; h++)
            W2T[h][c] = (h < Hn) ? (__bf16)Wg2[c * Hn + h] : (__bf16)0.f;
    }
    // ---- features for pair (i, j=tid) ----
    {
        int j = tid;
        float ci0 = centers[(b * Nn + i) * 3 + 0];
        float ci1 = centers[(b * Nn + i) * 3 + 1];
        float ci2 = centers[(b * Nn + i) * 3 + 2];
        float si0 = sizes[(b * Nn + i) * 3 + 0];
        float si1 = sizes[(b * Nn + i) * 3 + 1];
        float si2 = sizes[(b * Nn + i) * 3 + 2];
        float cj0 = centers[(b * Nn + j) * 3 + 0];
        float cj1 = centers[(b * Nn + j) * 3 + 1];
        float cj2 = centers[(b * Nn + j) * 3 + 2];
        float sj0 = sizes[(b * Nn + j) * 3 + 0];
        float sj1 = sizes[(b * Nn + j) * 3 + 1];
        float sj2 = sizes[(b * Nn + j) * 3 + 2];
        float rx = cj0 - ci0, ry = cj1 - ci1, rz = cj2 - ci2;
        float h2 = rx * rx + ry * ry;
        float dist = sqrtf(h2 + rz * rz);
        float horiz = sqrtf(h2);
        float f[24];
        f[0] = rx; f[1] = ry; f[2] = rz;
        f[3] = dist; f[4] = horiz;
        f[5] = rz / (dist + 1e-6f);
        f[6] = sj0 - si0; f[7] = sj1 - si1; f[8] = sj2 - si2;
        f[9] = sj0 / (si0 + 1e-6f);
        f[10] = sj1 / (si1 + 1e-6f);
        f[11] = sj2 / (si2 + 1e-6f);
        f[12] = 1.0f;  // bias feature -> W1 row 12 = bg1
        __bf16 tf[24];
#pragma unroll
        for (int k = 0; k < 13; k++) tf[k] = (__bf16)f[k];
#pragma unroll
        for (int k = 13; k < 24; k++) tf[k] = (__bf16)0.f;
        *(bf16x8*)&fT[j][0] = *(bf16x8*)&tf[0];
        *(bf16x8*)&fT[j][8] = *(bf16x8*)&tf[8];
        *(bf16x8*)&fT[j][16] = *(bf16x8*)&tf[16];
    }
    __syncthreads();

    int w = tid >> 6, l = tid & 63;
    int lr = l & 15, lg = l >> 4;  // A/B frag: row/col = lr, k = lg*8+e
    int jw = w * 64;
    bool hasK = (l < 32);  // k 16..31 are zero-padded: lanes 32..63 use zero frags

    bf16x8 zf;
#pragma unroll
    for (int e = 0; e < 8; e++) zf[e] = (__bf16)0.f;
    f32x4 zero4 = {0.f, 0.f, 0.f, 0.f};

    bf16x8 a1[4];
#pragma unroll
    for (int jt = 0; jt < 4; jt++)
        a1[jt] = hasK ? *(const bf16x8*)&fT[jw + jt * 16 + lr][lg * 8] : zf;

    f32x4 pacc[4];
#pragma unroll
    for (int jt = 0; jt < 4; jt++) pacc[jt] = zero4;

    for (int cc = 0; cc < 8; cc++) {  // c-chunk of 32
#pragma unroll
        for (int ct = 0; ct < 2; ct++) {
            int cg = cc * 2 + ct;
            bf16x8 b1 = hasK ? *(const bf16x8*)&W1T[cg * 16 + lr][lg * 8] : zf;
#pragma unroll
            for (int jt = 0; jt < 4; jt++) {
                f32x4 acc = __builtin_amdgcn_mfma_f32_16x16x32_bf16(a1[jt], b1, zero4, 0, 0, 0);
#pragma unroll
                for (int r = 0; r < 4; r++) {
                    float g = gelu_fast(acc[r]);
                    gbuf[w][jt * 16 + lg * 4 + r][ct * 16 + lr] = (__bf16)g;
                }
            }
        }
        // layer 2: K=32 over this chunk (same-wave write->read, compiler inserts lgkmcnt)
        bf16x8 b2 = *(const bf16x8*)&W2T[lr][cc * 32 + lg * 8];
#pragma unroll
        for (int jt = 0; jt < 4; jt++) {
            bf16x8 a2 = *(const bf16x8*)&gbuf[w][jt * 16 + lr][lg * 8];
            pacc[jt] = __builtin_amdgcn_mfma_f32_16x16x32_bf16(a2, b2, pacc[jt], 0, 0, 0);
        }
    }

    float alpha = alphap[0];
    if (lr < Hn) {  // D: col(h)=lr, row(j-local)=lg*4+r
        float hw_ = headw[b * Hn + lr];
        float bg = bg2[lr];
        float* dst = bias_eff + (((size_t)(b * Hn + lr)) * Nn + i) * Nn;
#pragma unroll
        for (int jt = 0; jt < 4; jt++)
#pragma unroll
            for (int r = 0; r < 4; r++)
                dst[jw + jt * 16 + lg * 4 + r] = alpha * hw_ * (pacc[jt][r] + bg);
    }
}

// ---------------- QKV projection, 8 rows per block ----------------
__global__ void __launch_bounds__(256) k_qkv(const float* __restrict__ xn,
                                             const float* __restrict__ W,
                                             const float* __restrict__ bqkv,
                                             float* __restrict__ qb, float* __restrict__ kb,
                                             float* __restrict__ vb) {
    __shared__ float xrT[Cn][8];
    int r0 = blockIdx.x * 8;
    int tid = threadIdx.x;
    for (int r = 0; r < 8; r++) xrT[tid][r] = xn[(size_t)(r0 + r) * Cn + tid];
    __syncthreads();
    for (int s = 0; s < 3; s++) {
        int o = s * Cn + tid;
        float bias = bqkv[o];
        float acc[8];
#pragma unroll
        for (int r = 0; r < 8; r++) acc[r] = bias;
        for (int i2 = 0; i2 < Cn; i2++) {
            float w = W[(size_t)i2 * (3 * Cn) + o];
            float4 x0 = *(const float4*)&xrT[i2][0];
            float4 x1 = *(const float4*)&xrT[i2][4];
            acc[0] = fmaf(x0.x, w, acc[0]);
            acc[1] = fmaf(x0.y, w, acc[1]);
            acc[2] = fmaf(x0.z, w, acc[2]);
            acc[3] = fmaf(x0.w, w, acc[3]);
            acc[4] = fmaf(x1.x, w, acc[4]);
            acc[5] = fmaf(x1.y, w, acc[5]);
            acc[6] = fmaf(x1.z, w, acc[6]);
            acc[7] = fmaf(x1.w, w, acc[7]);
        }
        float* dst = (s == 0) ? qb : ((s == 1) ? kb : vb);
        int hh = tid >> 6, hd = tid & 63;
#pragma unroll
        for (int r = 0; r < 8; r++) {
            int row = r0 + r;
            int bb = row >> 8, n = row & 255;
            dst[(((size_t)bb * Hn + hh) * Nn + n) * HDn + hd] = acc[r];
        }
    }
}

// ---------------- attention: 32 query rows per block ----------------
__global__ void __launch_bounds__(256) k_attn(const float* __restrict__ qb,
                                              const float* __restrict__ kb,
                                              const float* __restrict__ vb,
                                              const float* __restrict__ bias_eff,
                                              const unsigned char* __restrict__ knn,
                                              float* __restrict__ attn_out,
                                              float* __restrict__ hout) {
    __shared__ float qs[32][HDn];
    __shared__ float L[32][Nn];
    int blk = blockIdx.x;
    int bh = blk >> 3, it = blk & 7;
    int i0 = it * 32;
    int b = bh >> 2, h = bh & 3;
    int tid = threadIdx.x;

    for (int r = 0; r < 8; r++) {
        int idx = r * 256 + tid;
        int ii = idx >> 6, d = idx & 63;
        qs[ii][d] = qb[((size_t)bh * Nn + i0 + ii) * HDn + d];
    }
    float kr[HDn];
    {
        const float4* kp = (const float4*)(kb + ((size_t)bh * Nn + tid) * HDn);
#pragma unroll
        for (int d4 = 0; d4 < 16; d4++) {
            float4 t = kp[d4];
            kr[d4 * 4 + 0] = t.x;
            kr[d4 * 4 + 1] = t.y;
            kr[d4 * 4 + 2] = t.z;
            kr[d4 * 4 + 3] = t.w;
        }
    }
    __syncthreads();

    int j = tid;
    for (int ii = 0; ii < 32; ii++) {
        float acc = 0.0f;
#pragma unroll
        for (int d4 = 0; d4 < 16; d4++) {
            float4 qv = *(const float4*)&qs[ii][d4 * 4];
            acc = fmaf(qv.x, kr[d4 * 4 + 0], acc);
            acc = fmaf(qv.y, kr[d4 * 4 + 1], acc);
            acc = fmaf(qv.z, kr[d4 * 4 + 2], acc);
            acc = fmaf(qv.w, kr[d4 * 4 + 3], acc);
        }
        int ig = i0 + ii;
        float lg = fmaf(acc, 0.125f, bias_eff[((size_t)bh * Nn + ig) * Nn + j]);
        bool m = knn[((size_t)(b * Nn + ig)) * Nn + j] != 0;
        L[ii][j] = m ? lg : -1e9f;
    }
    __syncthreads();

    int r = tid >> 3, kk = tid & 7;
    float mx = -1e30f;
    for (int m8 = 0; m8 < 32; m8++) mx = fmaxf(mx, L[r][kk + 8 * m8]);
    mx = fmaxf(mx, __shfl_xor(mx, 1, 64));
    mx = fmaxf(mx, __shfl_xor(mx, 2, 64));
    mx = fmaxf(mx, __shfl_xor(mx, 4, 64));
    float s = 0.0f;
    for (int m8 = 0; m8 < 32; m8++) {
        float e = __builtin_amdgcn_exp2f((L[r][kk + 8 * m8] - mx) * 1.44269504f);
        s += e;
        L[r][kk + 8 * m8] = e;
    }
    s += __shfl_xor(s, 1, 64);
    s += __shfl_xor(s, 2, 64);
    s += __shfl_xor(s, 4, 64);
    float inv = 1.0f / s;
    for (int m8 = 0; m8 < 32; m8++) {
        float a = L[r][kk + 8 * m8] * inv;
        L[r][kk + 8 * m8] = a;
        attn_out[((size_t)bh * Nn + i0 + r) * Nn + kk + 8 * m8] = a;
    }
    __syncthreads();

    int w = tid >> 6, d = tid & 63;
    float acc8[8] = {0.f, 0.f, 0.f, 0.f, 0.f, 0.f, 0.f, 0.f};
    for (int t4 = 0; t4 < 64; t4++) {
        int t = t4 * 4;
        float v0 = vb[((size_t)bh * Nn + t + 0) * HDn + d];
        float v1 = vb[((size_t)bh * Nn + t + 1) * HDn + d];
        float v2 = vb[((size_t)bh * Nn + t + 2) * HDn + d];
        float v3 = vb[((size_t)bh * Nn + t + 3) * HDn + d];
#pragma unroll
        for (int k8 = 0; k8 < 8; k8++) {
            float4 a4 = *(const float4*)&L[w + 4 * k8][t];
            acc8[k8] = fmaf(a4.x, v0, fmaf(a4.y, v1, fmaf(a4.z, v2, fmaf(a4.w, v3, acc8[k8]))));
        }
    }
#pragma unroll
    for (int k8 = 0; k8 < 8; k8++) {
        int ig = i0 + w + 4 * k8;
        hout[((size_t)(b * Nn + ig)) * Cn + h * HDn + d] = acc8[k8];
    }
}

// ---------------- output projection + residual ----------------
__global__ void __launch_bounds__(256) k_proj(const float* __restrict__ hout,
                                              const float* __restrict__ Wp,
                                              const float* __restrict__ bp,
                                              const float* __restrict__ x,
                                              float* __restrict__ xout) {
    __shared__ float hrT[Cn][8];
    int r0 = blockIdx.x * 8;
    int tid = threadIdx.x;
    for (int r = 0; r < 8; r++) hrT[tid][r] = hout[(size_t)(r0 + r) * Cn + tid];
    __syncthreads();
    float acc[8];
    float bias = bp[tid];
#pragma unroll
    for (int r = 0; r < 8; r++) acc[r] = bias;
    for (int i2 = 0; i2 < Cn; i2++) {
        float w = Wp[(size_t)i2 * Cn + tid];
        float4 x0 = *(const float4*)&hrT[i2][0];
        float4 x1 = *(const float4*)&hrT[i2][4];
        acc[0] = fmaf(x0.x, w, acc[0]);
        acc[1] = fmaf(x0.y, w, acc[1]);
        acc[2] = fmaf(x0.z, w, acc[2]);
        acc[3] = fmaf(x0.w, w, acc[3]);
        acc[4] = fmaf(x1.x, w, acc[4]);
        acc[5] = fmaf(x1.y, w, acc[5]);
        acc[6] = fmaf(x1.z, w, acc[6]);
        acc[7] = fmaf(x1.w, w, acc[7]);
    }
#pragma unroll
    for (int r = 0; r < 8; r++) {
        size_t idx = (size_t)(r0 + r) * Cn + tid;
        xout[idx] = x[idx] + acc[r];
    }
}

extern "C" void kernel_launch(void* const* d_in, const int* in_sizes, int n_in,
                              void* d_out, int out_size, void* d_ws, size_t ws_size,
                              hipStream_t stream) {
    const float* x       = (const float*)d_in[0];
    const float* lang    = (const float*)d_in[1];
    const float* centers = (const float*)d_in[2];
    const float* corners = (const float*)d_in[3];
    const int*   obj     = (const int*)d_in[4];
    const float* ln_g    = (const float*)d_in[5];
    const float* ln_b    = (const float*)d_in[6];
    const float* W_qkv   = (const float*)d_in[7];
    const float* b_qkv   = (const float*)d_in[8];
    const float* W_proj  = (const float*)d_in[9];
    const float* b_proj  = (const float*)d_in[10];
    const float* Wg1     = (const float*)d_in[11];
    const float* bg1     = (const float*)d_in[12];
    const float* Wg2     = (const float*)d_in[13];
    const float* bg2     = (const float*)d_in[14];
    const float* Wt1     = (const float*)d_in[15];
    const float* bt1     = (const float*)d_in[16];
    const float* Wt2     = (const float*)d_in[17];
    const float* bt2     = (const float*)d_in[18];
    const float* alpha   = (const float*)d_in[19];

    float* out = (float*)d_out;
    float* xout     = out;                 // BL*N*C
    float* attn     = out + 1048576;       // BL*H*N*N
    float* bias_eff = out + 5242880;       // BL*H*N*N

    float* ws = (float*)d_ws;
    float* xn    = ws;                // 1048576
    float* qb    = xn + 1048576;      // 1048576
    float* kb    = qb + 1048576;      // 1048576
    float* vb    = kb + 1048576;      // 1048576
    float* hout  = vb + 1048576;      // 1048576
    float* sizes = hout + 1048576;    // 12288
    float* headw = sizes + 12288;     // 64
    unsigned char* knn = (unsigned char*)(headw + 64);  // 1 MiB

    k_sizes<<<BLn, Nn, 0, stream>>>(corners, sizes);
    k_ln<<<BLn * Nn, Cn, 0, stream>>>(x, ln_g, ln_b, xn);
    k_headw<<<BLn, Cn, 0, stream>>>(lang, Wt1, bt1, Wt2, bt2, headw);
    k_knn<<<BLn * Nn, Nn, 0, stream>>>(centers, obj, knn);
    k_qkv<<<BLn * Nn / 8, Cn, 0, stream>>>(xn, W_qkv, b_qkv, qb, kb, vb);
    k_geombias<<<BLn * Nn, Nn, 0, stream>>>(centers, sizes, Wg1, bg1, Wg2, bg2, headw, alpha,
                                            bias_eff);
    k_attn<<<BLn * Hn * Nn / 32, Nn, 0, stream>>>(qb, kb, vb, bias_eff, knn, attn, hout);
    k_proj<<<BLn * Nn / 8, Cn, 0, stream>>>(hout, W_proj, b_proj, x, xout);
}

// Round 4
// 232.796 us; speedup vs baseline: 2.5657x; 1.1401x over previous
//
#include <hip/hip_runtime.h>
#include <math.h>

#define BLn 16
#define Nn 256
#define Tn 32
#define Cn 256
#define Hn 4
#define HDn 64
#define KREL 32

typedef float f32x4 __attribute__((ext_vector_type(4)));
typedef __bf16 bf16x8 __attribute__((ext_vector_type(8)));

__device__ __forceinline__ float gelu_exact(float x) {
    return 0.5f * x * (1.0f + erff(x * 0.70710678118654752440f));
}

// sigmoid-form gelu: x * sigma(1.702 x). |t| <~ 1 in this net -> |err| <= ~5e-3 on g,
// amplified to <1e-4 on bias_eff (w2~0.02, alpha=0.05). 3 VALU + 2 trans ops.
__device__ __forceinline__ float gelu_sig(float x) {
    float e = __builtin_amdgcn_exp2f(-2.4554669f * x);  // -1.702*log2(e)*x
    return x * __builtin_amdgcn_rcpf(1.0f + e);
}

// ---------------- fused prep: ln | knn | sizes | headw ----------------
__global__ void __launch_bounds__(256) k_prep(
    const float* __restrict__ x, const float* __restrict__ ln_g, const float* __restrict__ ln_b,
    float* __restrict__ xn, const float* __restrict__ centers, const int* __restrict__ obj,
    unsigned char* __restrict__ knn, const float* __restrict__ corners,
    float* __restrict__ sizes, const float* __restrict__ lang, const float* __restrict__ Wt1,
    const float* __restrict__ bt1, const float* __restrict__ Wt2, const float* __restrict__ bt2,
    float* __restrict__ headw) {
    __shared__ float sm0[Nn];  // knn d2s | headw sent
    __shared__ float sm1[Nn];  // headw t1
    __shared__ float ss[4], qq[4];
    int blk = blockIdx.x;
    int tid = threadIdx.x;

    if (blk < 4096) {  // ---- LayerNorm ----
        int row = blk;
        int c = tid;
        float v = x[(size_t)row * Cn + c];
        float s = v, q = v * v;
        for (int m = 32; m > 0; m >>= 1) {
            s += __shfl_xor(s, m, 64);
            q += __shfl_xor(q, m, 64);
        }
        int w = c >> 6, l = c & 63;
        if (l == 0) { ss[w] = s; qq[w] = q; }
        __syncthreads();
        s = ss[0] + ss[1] + ss[2] + ss[3];
        q = qq[0] + qq[1] + qq[2] + qq[3];
        float mu = s * (1.0f / Cn);
        float var = q * (1.0f / Cn) - mu * mu;
        float r = rsqrtf(var + 1e-5f);
        xn[(size_t)row * Cn + c] = (v - mu) * r * ln_g[c] + ln_b[c];
    } else if (blk < 8192) {  // ---- KNN + pair mask ----
        int bi = blk - 4096;
        int b = bi >> 8, i = bi & 255;
        int j = tid;
        float cx = centers[(b * Nn + i) * 3 + 0];
        float cy = centers[(b * Nn + i) * 3 + 1];
        float cz = centers[(b * Nn + i) * 3 + 2];
        float dx = centers[(b * Nn + j) * 3 + 0] - cx;
        float dy = centers[(b * Nn + j) * 3 + 1] - cy;
        float dz = centers[(b * Nn + j) * 3 + 2] - cz;
        float dd = sqrtf(dx * dx + dy * dy + dz * dz);
        sm0[j] = dd;
        __syncthreads();
        int rank = 0;
        for (int t = 0; t < Nn; t++) {
            float o = sm0[t];
            rank += (o < dd) || (o == dd && t < j);
        }
        bool m = (rank < KREL);
        m = m && (obj[b * Nn + i] != 0) && (obj[b * Nn + j] != 0);
        knn[(size_t)bi * Nn + j] = m ? 1 : 0;
    } else if (blk < 8208) {  // ---- sizes ----
        int b = blk - 8192, n = tid;
        const float* p = corners + (size_t)((b * Nn + n) * 8) * 3;
        float mn[3] = {1e30f, 1e30f, 1e30f}, mx[3] = {-1e30f, -1e30f, -1e30f};
        for (int v = 0; v < 8; v++)
            for (int d = 0; d < 3; d++) {
                float t = p[v * 3 + d];
                mn[d] = fminf(mn[d], t);
                mx[d] = fmaxf(mx[d], t);
            }
        for (int d = 0; d < 3; d++) sizes[(b * Nn + n) * 3 + d] = mx[d] - mn[d];
    } else {  // ---- head weights ----
        int b = blk - 8208, c = tid;
        float s = 0.0f;
        for (int t = 0; t < Tn; t++) s += lang[((size_t)b * Tn + t) * Cn + c];
        sm0[c] = s * (1.0f / Tn);
        __syncthreads();
        float acc = bt1[c];
        for (int i = 0; i < Cn; i++) acc += sm0[i] * Wt1[i * Cn + c];
        sm1[c] = gelu_exact(acc);
        __syncthreads();
        if (c < Hn) {
            float a = bt2[c];
            for (int i = 0; i < Cn; i++) a += sm1[i] * Wt2[i * Hn + c];
            headw[b * Hn + c] = 1.0f / (1.0f + expf(-a));
        }
    }
}

// ---------------- pairwise geometry bias MLP, swapped-operand MFMA ----------------
// L1: D = W1^T(c rows) x f(j cols): lane holds 4 consecutive c for one j ->
// gelu + packed 8B LDS write. L2: g[j][c] @ W2 accumulated over 8 c-chunks.
__global__ void __launch_bounds__(256) k_geombias(
    const float* __restrict__ centers, const float* __restrict__ sizes,
    const float* __restrict__ Wg1, const float* __restrict__ bg1,
    const float* __restrict__ Wg2, const float* __restrict__ bg2,
    const float* __restrict__ headw, const float* __restrict__ alphap,
    float* __restrict__ bias_eff) {
    __shared__ __bf16 fT[Nn][24];      // [j][k]  B-frag (j cols)      12.0 KB
    __shared__ __bf16 W1T[Cn][24];     // [c][k]  A-frag (c rows)      12.0 KB
    __shared__ __bf16 W2T[4][264];     // [h][c]  B-frag, h<4 real      2.06 KB
    __shared__ __bf16 gbuf[4][64][40]; // per-wave [j][c-chunk(32)+pad] 20.0 KB

    int bi = blockIdx.x;
    int b = bi >> 8, i = bi & 255;
    int tid = threadIdx.x;

    // ---- stage weights (thread = c) ----
    {
        int c = tid;
        __bf16 t1[24];
#pragma unroll
        for (int k = 0; k < 12; k++) t1[k] = (__bf16)Wg1[k * Cn + c];
        t1[12] = (__bf16)bg1[c];
#pragma unroll
        for (int k = 13; k < 24; k++) t1[k] = (__bf16)0.f;
        *(bf16x8*)&W1T[c][0] = *(bf16x8*)&t1[0];
        *(bf16x8*)&W1T[c][8] = *(bf16x8*)&t1[8];
        *(bf16x8*)&W1T[c][16] = *(bf16x8*)&t1[16];
#pragma unroll
        for (int h = 0; h < Hn; h++) W2T[h][c] = (__bf16)Wg2[c * Hn + h];
    }
    // ---- features for pair (i, j=tid) ----
    {
        int j = tid;
        float ci0 = centers[(b * Nn + i) * 3 + 0];
        float ci1 = centers[(b * Nn + i) * 3 + 1];
        float ci2 = centers[(b * Nn + i) * 3 + 2];
        float si0 = sizes[(b * Nn + i) * 3 + 0];
        float si1 = sizes[(b * Nn + i) * 3 + 1];
        float si2 = sizes[(b * Nn + i) * 3 + 2];
        float cj0 = centers[(b * Nn + j) * 3 + 0];
        float cj1 = centers[(b * Nn + j) * 3 + 1];
        float cj2 = centers[(b * Nn + j) * 3 + 2];
        float sj0 = sizes[(b * Nn + j) * 3 + 0];
        float sj1 = sizes[(b * Nn + j) * 3 + 1];
        float sj2 = sizes[(b * Nn + j) * 3 + 2];
        float rx = cj0 - ci0, ry = cj1 - ci1, rz = cj2 - ci2;
        float h2 = rx * rx + ry * ry;
        float dist = sqrtf(h2 + rz * rz);
        float horiz = sqrtf(h2);
        float f[24];
        f[0] = rx; f[1] = ry; f[2] = rz;
        f[3] = dist; f[4] = horiz;
        f[5] = rz / (dist + 1e-6f);
        f[6] = sj0 - si0; f[7] = sj1 - si1; f[8] = sj2 - si2;
        f[9] = sj0 / (si0 + 1e-6f);
        f[10] = sj1 / (si1 + 1e-6f);
        f[11] = sj2 / (si2 + 1e-6f);
        f[12] = 1.0f;  // bias feature -> W1 row 12 = bg1
        __bf16 tf[24];
#pragma unroll
        for (int k = 0; k < 13; k++) tf[k] = (__bf16)f[k];
#pragma unroll
        for (int k = 13; k < 24; k++) tf[k] = (__bf16)0.f;
        *(bf16x8*)&fT[j][0] = *(bf16x8*)&tf[0];
        *(bf16x8*)&fT[j][8] = *(bf16x8*)&tf[8];
        *(bf16x8*)&fT[j][16] = *(bf16x8*)&tf[16];
    }
    __syncthreads();

    int w = tid >> 6, l = tid & 63;
    int lr = l & 15, lg = l >> 4;
    int jw = w * 64;
    bool hasK = (l < 32);  // k 16..31 zero-padded

    bf16x8 zf;
#pragma unroll
    for (int e = 0; e < 8; e++) zf[e] = (__bf16)0.f;
    f32x4 zero4 = {0.f, 0.f, 0.f, 0.f};

    // feature B-frags for this wave's 4 j-tiles
    bf16x8 bf_[4];
#pragma unroll
    for (int jt = 0; jt < 4; jt++)
        bf_[jt] = hasK ? *(const bf16x8*)&fT[jw + jt * 16 + lr][lg * 8] : zf;

    f32x4 pacc[4];
#pragma unroll
    for (int jt = 0; jt < 4; jt++) pacc[jt] = zero4;

    for (int cc = 0; cc < 8; cc++) {
#pragma unroll
        for (int ct = 0; ct < 2; ct++) {
            int cbase = cc * 32 + ct * 16;
            bf16x8 aw = hasK ? *(const bf16x8*)&W1T[cbase + lr][lg * 8] : zf;
#pragma unroll
            for (int jt = 0; jt < 4; jt++) {
                // D: row (c-local) = lg*4+r, col (j-local) = lr
                f32x4 acc = __builtin_amdgcn_mfma_f32_16x16x32_bf16(aw, bf_[jt], zero4, 0, 0, 0);
                __bf16 gv[4];
#pragma unroll
                for (int r = 0; r < 4; r++) gv[r] = (__bf16)gelu_sig(acc[r]);
                *(uint2*)&gbuf[w][jt * 16 + lr][ct * 16 + lg * 4] = *(uint2*)&gv[0];
            }
        }
        // layer 2 over this 32-c chunk (same-wave write->read)
        bf16x8 b2 = (lr < Hn) ? *(const bf16x8*)&W2T[lr][cc * 32 + lg * 8] : zf;
#pragma unroll
        for (int jt = 0; jt < 4; jt++) {
            bf16x8 a2 = *(const bf16x8*)&gbuf[w][jt * 16 + lr][lg * 8];
            pacc[jt] = __builtin_amdgcn_mfma_f32_16x16x32_bf16(a2, b2, pacc[jt], 0, 0, 0);
        }
    }

    float alpha = alphap[0];
    if (lr < Hn) {  // D: col(h)=lr, row(j-local)=lg*4+r
        float hw_ = headw[b * Hn + lr];
        float bg = bg2[lr];
        float* dst = bias_eff + (((size_t)(b * Hn + lr)) * Nn + i) * Nn;
#pragma unroll
        for (int jt = 0; jt < 4; jt++)
#pragma unroll
            for (int r = 0; r < 4; r++)
                dst[jw + jt * 16 + lg * 4 + r] = alpha * hw_ * (pacc[jt][r] + bg);
    }
}

// ---------------- QKV projection, 8 rows per block ----------------
__global__ void __launch_bounds__(256) k_qkv(const float* __restrict__ xn,
                                             const float* __restrict__ W,
                                             const float* __restrict__ bqkv,
                                             float* __restrict__ qb, float* __restrict__ kb,
                                             float* __restrict__ vb) {
    __shared__ float xrT[Cn][8];
    int r0 = blockIdx.x * 8;
    int tid = threadIdx.x;
    for (int r = 0; r < 8; r++) xrT[tid][r] = xn[(size_t)(r0 + r) * Cn + tid];
    __syncthreads();
    for (int s = 0; s < 3; s++) {
        int o = s * Cn + tid;
        float bias = bqkv[o];
        float acc[8];
#pragma unroll
        for (int r = 0; r < 8; r++) acc[r] = bias;
        for (int i2 = 0; i2 < Cn; i2++) {
            float w = W[(size_t)i2 * (3 * Cn) + o];
            float4 x0 = *(const float4*)&xrT[i2][0];
            float4 x1 = *(const float4*)&xrT[i2][4];
            acc[0] = fmaf(x0.x, w, acc[0]);
            acc[1] = fmaf(x0.y, w, acc[1]);
            acc[2] = fmaf(x0.z, w, acc[2]);
            acc[3] = fmaf(x0.w, w, acc[3]);
            acc[4] = fmaf(x1.x, w, acc[4]);
            acc[5] = fmaf(x1.y, w, acc[5]);
            acc[6] = fmaf(x1.z, w, acc[6]);
            acc[7] = fmaf(x1.w, w, acc[7]);
        }
        float* dst = (s == 0) ? qb : ((s == 1) ? kb : vb);
        int hh = tid >> 6, hd = tid & 63;
#pragma unroll
        for (int r = 0; r < 8; r++) {
            int row = r0 + r;
            int bb = row >> 8, n = row & 255;
            dst[(((size_t)bb * Hn + hh) * Nn + n) * HDn + hd] = acc[r];
        }
    }
}

// ---------------- attention: 32 query rows per block ----------------
__global__ void __launch_bounds__(256) k_attn(const float* __restrict__ qb,
                                              const float* __restrict__ kb,
                                              const float* __restrict__ vb,
                                              const float* __restrict__ bias_eff,
                                              const unsigned char* __restrict__ knn,
                                              float* __restrict__ attn_out,
                                              float* __restrict__ hout) {
    __shared__ float qs[32][HDn];
    __shared__ float L[32][264];  // padded: softmax strided access 2-way max
    int blk = blockIdx.x;
    int bh = blk >> 3, it = blk & 7;
    int i0 = it * 32;
    int b = bh >> 2, h = bh & 3;
    int tid = threadIdx.x;

    for (int r = 0; r < 8; r++) {
        int idx = r * 256 + tid;
        int ii = idx >> 6, d = idx & 63;
        qs[ii][d] = qb[((size_t)bh * Nn + i0 + ii) * HDn + d];
    }
    float kr[HDn];
    {
        const float4* kp = (const float4*)(kb + ((size_t)bh * Nn + tid) * HDn);
#pragma unroll
        for (int d4 = 0; d4 < 16; d4++) {
            float4 t = kp[d4];
            kr[d4 * 4 + 0] = t.x;
            kr[d4 * 4 + 1] = t.y;
            kr[d4 * 4 + 2] = t.z;
            kr[d4 * 4 + 3] = t.w;
        }
    }
    __syncthreads();

    int j = tid;
    for (int ii = 0; ii < 32; ii++) {
        float acc = 0.0f;
#pragma unroll
        for (int d4 = 0; d4 < 16; d4++) {
            float4 qv = *(const float4*)&qs[ii][d4 * 4];
            acc = fmaf(qv.x, kr[d4 * 4 + 0], acc);
            acc = fmaf(qv.y, kr[d4 * 4 + 1], acc);
            acc = fmaf(qv.z, kr[d4 * 4 + 2], acc);
            acc = fmaf(qv.w, kr[d4 * 4 + 3], acc);
        }
        int ig = i0 + ii;
        float lg = fmaf(acc, 0.125f, bias_eff[((size_t)bh * Nn + ig) * Nn + j]);
        bool m = knn[((size_t)(b * Nn + ig)) * Nn + j] != 0;
        L[ii][j] = m ? lg : -1e9f;
    }
    __syncthreads();

    int r = tid >> 3, kk = tid & 7;
    float mx = -1e30f;
    for (int m8 = 0; m8 < 32; m8++) mx = fmaxf(mx, L[r][kk + 8 * m8]);
    mx = fmaxf(mx, __shfl_xor(mx, 1, 64));
    mx = fmaxf(mx, __shfl_xor(mx, 2, 64));
    mx = fmaxf(mx, __shfl_xor(mx, 4, 64));
    float s = 0.0f;
    for (int m8 = 0; m8 < 32; m8++) {
        float e = __builtin_amdgcn_exp2f((L[r][kk + 8 * m8] - mx) * 1.44269504f);
        s += e;
        L[r][kk + 8 * m8] = e;
    }
    s += __shfl_xor(s, 1, 64);
    s += __shfl_xor(s, 2, 64);
    s += __shfl_xor(s, 4, 64);
    float inv = 1.0f / s;
    for (int m8 = 0; m8 < 32; m8++) L[r][kk + 8 * m8] *= inv;
    __syncthreads();

    // coalesced attn write
    for (int rr = 0; rr < 32; rr++)
        attn_out[((size_t)bh * Nn + i0 + rr) * Nn + tid] = L[rr][tid];

    // PV: wave w handles rows {w, w+4, ..., w+28}, lane d = output dim
    int w = tid >> 6, d = tid & 63;
    float acc8[8] = {0.f, 0.f, 0.f, 0.f, 0.f, 0.f, 0.f, 0.f};
    for (int t4 = 0; t4 < 64; t4++) {
        int t = t4 * 4;
        float v0 = vb[((size_t)bh * Nn + t + 0) * HDn + d];
        float v1 = vb[((size_t)bh * Nn + t + 1) * HDn + d];
        float v2 = vb[((size_t)bh * Nn + t + 2) * HDn + d];
        float v3 = vb[((size_t)bh * Nn + t + 3) * HDn + d];
#pragma unroll
        for (int k8 = 0; k8 < 8; k8++) {
            float4 a4 = *(const float4*)&L[w + 4 * k8][t];
            acc8[k8] = fmaf(a4.x, v0, fmaf(a4.y, v1, fmaf(a4.z, v2, fmaf(a4.w, v3, acc8[k8]))));
        }
    }
#pragma unroll
    for (int k8 = 0; k8 < 8; k8++) {
        int ig = i0 + w + 4 * k8;
        hout[((size_t)(b * Nn + ig)) * Cn + h * HDn + d] = acc8[k8];
    }
}

// ---------------- output projection + residual ----------------
__global__ void __launch_bounds__(256) k_proj(const float* __restrict__ hout,
                                              const float* __restrict__ Wp,
                                              const float* __restrict__ bp,
                                              const float* __restrict__ x,
                                              float* __restrict__ xout) {
    __shared__ float hrT[Cn][8];
    int r0 = blockIdx.x * 8;
    int tid = threadIdx.x;
    for (int r = 0; r < 8; r++) hrT[tid][r] = hout[(size_t)(r0 + r) * Cn + tid];
    __syncthreads();
    float acc[8];
    float bias = bp[tid];
#pragma unroll
    for (int r = 0; r < 8; r++) acc[r] = bias;
    for (int i2 = 0; i2 < Cn; i2++) {
        float w = Wp[(size_t)i2 * Cn + tid];
        float4 x0 = *(const float4*)&hrT[i2][0];
        float4 x1 = *(const float4*)&hrT[i2][4];
        acc[0] = fmaf(x0.x, w, acc[0]);
        acc[1] = fmaf(x0.y, w, acc[1]);
        acc[2] = fmaf(x0.z, w, acc[2]);
        acc[3] = fmaf(x0.w, w, acc[3]);
        acc[4] = fmaf(x1.x, w, acc[4]);
        acc[5] = fmaf(x1.y, w, acc[5]);
        acc[6] = fmaf(x1.z, w, acc[6]);
        acc[7] = fmaf(x1.w, w, acc[7]);
    }
#pragma unroll
    for (int r = 0; r < 8; r++) {
        size_t idx = (size_t)(r0 + r) * Cn + tid;
        xout[idx] = x[idx] + acc[r];
    }
}

extern "C" void kernel_launch(void* const* d_in, const int* in_sizes, int n_in,
                              void* d_out, int out_size, void* d_ws, size_t ws_size,
                              hipStream_t stream) {
    const float* x       = (const float*)d_in[0];
    const float* lang    = (const float*)d_in[1];
    const float* centers = (const float*)d_in[2];
    const float* corners = (const float*)d_in[3];
    const int*   obj     = (const int*)d_in[4];
    const float* ln_g    = (const float*)d_in[5];
    const float* ln_b    = (const float*)d_in[6];
    const float* W_qkv   = (const float*)d_in[7];
    const float* b_qkv   = (const float*)d_in[8];
    const float* W_proj  = (const float*)d_in[9];
    const float* b_proj  = (const float*)d_in[10];
    const float* Wg1     = (const float*)d_in[11];
    const float* bg1     = (const float*)d_in[12];
    const float* Wg2     = (const float*)d_in[13];
    const float* bg2     = (const float*)d_in[14];
    const float* Wt1     = (const float*)d_in[15];
    const float* bt1     = (const float*)d_in[16];
    const float* Wt2     = (const float*)d_in[17];
    const float* bt2     = (const float*)d_in[18];
    const float* alpha   = (const float*)d_in[19];

    float* out = (float*)d_out;
    float* xout     = out;                 // BL*N*C
    float* attn     = out + 1048576;       // BL*H*N*N
    float* bias_eff = out + 5242880;       // BL*H*N*N

    float* ws = (float*)d_ws;
    float* xn    = ws;                // 1048576
    float* qb    = xn + 1048576;      // 1048576
    float* kb    = qb + 1048576;      // 1048576
    float* vb    = kb + 1048576;      // 1048576
    float* hout  = vb + 1048576;      // 1048576
    float* sizes = hout + 1048576;    // 12288
    float* headw = sizes + 12288;     // 64
    unsigned char* knn = (unsigned char*)(headw + 64);  // 1 MiB

    k_prep<<<8224, 256, 0, stream>>>(x, ln_g, ln_b, xn, centers, obj, knn, corners, sizes,
                                     lang, Wt1, bt1, Wt2, bt2, headw);
    k_geombias<<<BLn * Nn, Nn, 0, stream>>>(centers, sizes, Wg1, bg1, Wg2, bg2, headw, alpha,
                                            bias_eff);
    k_qkv<<<BLn * Nn / 8, Cn, 0, stream>>>(xn, W_qkv, b_qkv, qb, kb, vb);
    k_attn<<<BLn * Hn * Nn / 32, Nn, 0, stream>>>(qb, kb, vb, bias_eff, knn, attn, hout);
    k_proj<<<BLn * Nn / 8, Cn, 0, stream>>>(hout, W_proj, b_proj, x, xout);
}

// Round 5
// 163.409 us; speedup vs baseline: 3.6551x; 1.4246x over previous
//
#include <hip/hip_runtime.h>
#include <math.h>

#define BLn 16
#define Nn 256
#define Tn 32
#define Cn 256
#define Hn 4
#define HDn 64
#define KREL 32

typedef float f32x4 __attribute__((ext_vector_type(4)));
typedef __bf16 bf16x8 __attribute__((ext_vector_type(8)));

#define MFMA16(a, b, c) __builtin_amdgcn_mfma_f32_16x16x32_bf16(a, b, c, 0, 0, 0)

__device__ __forceinline__ float gelu_exact(float x) {
    return 0.5f * x * (1.0f + erff(x * 0.70710678118654752440f));
}

// sigmoid-form gelu (validated r4: absmax 0.0078 total)
__device__ __forceinline__ float gelu_sig(float x) {
    float e = __builtin_amdgcn_exp2f(-2.4554669f * x);
    return x * __builtin_amdgcn_rcpf(1.0f + e);
}

// ---------------- fused prep: ln | knn | sizes | headw | W transposes ----------------
__global__ void __launch_bounds__(256) k_prep(
    const float* __restrict__ x, const float* __restrict__ ln_g, const float* __restrict__ ln_b,
    __bf16* __restrict__ xnb, const float* __restrict__ centers, const int* __restrict__ obj,
    unsigned char* __restrict__ knn, const float* __restrict__ corners,
    float* __restrict__ sizes, const float* __restrict__ lang, const float* __restrict__ Wt1,
    const float* __restrict__ bt1, const float* __restrict__ Wt2, const float* __restrict__ bt2,
    float* __restrict__ headw, const float* __restrict__ W_qkv, __bf16* __restrict__ wqT,
    const float* __restrict__ W_proj, __bf16* __restrict__ wpT) {
    __shared__ float sm0[Nn];
    __shared__ float sm1[Nn];
    __shared__ float ss[4], qq[4];
    __shared__ float T[64][65];
    int blk = blockIdx.x;
    int tid = threadIdx.x;

    if (blk < 4096) {  // ---- LayerNorm -> bf16 ----
        int row = blk;
        int c = tid;
        float v = x[(size_t)row * Cn + c];
        float s = v, q = v * v;
        for (int m = 32; m > 0; m >>= 1) {
            s += __shfl_xor(s, m, 64);
            q += __shfl_xor(q, m, 64);
        }
        int w = c >> 6, l = c & 63;
        if (l == 0) { ss[w] = s; qq[w] = q; }
        __syncthreads();
        s = ss[0] + ss[1] + ss[2] + ss[3];
        q = qq[0] + qq[1] + qq[2] + qq[3];
        float mu = s * (1.0f / Cn);
        float var = q * (1.0f / Cn) - mu * mu;
        float r = rsqrtf(var + 1e-5f);
        xnb[(size_t)row * Cn + c] = (__bf16)((v - mu) * r * ln_g[c] + ln_b[c]);
    } else if (blk < 8192) {  // ---- KNN + pair mask ----
        int bi = blk - 4096;
        int b = bi >> 8, i = bi & 255;
        int j = tid;
        float cx = centers[(b * Nn + i) * 3 + 0];
        float cy = centers[(b * Nn + i) * 3 + 1];
        float cz = centers[(b * Nn + i) * 3 + 2];
        float dx = centers[(b * Nn + j) * 3 + 0] - cx;
        float dy = centers[(b * Nn + j) * 3 + 1] - cy;
        float dz = centers[(b * Nn + j) * 3 + 2] - cz;
        float dd = sqrtf(dx * dx + dy * dy + dz * dz);
        sm0[j] = dd;
        __syncthreads();
        int rank = 0;
        for (int t = 0; t < Nn; t++) {
            float o = sm0[t];
            rank += (o < dd) || (o == dd && t < j);
        }
        bool m = (rank < KREL);
        m = m && (obj[b * Nn + i] != 0) && (obj[b * Nn + j] != 0);
        knn[(size_t)bi * Nn + j] = m ? 1 : 0;
    } else if (blk < 8208) {  // ---- sizes ----
        int b = blk - 8192, n = tid;
        const float* p = corners + (size_t)((b * Nn + n) * 8) * 3;
        float mn[3] = {1e30f, 1e30f, 1e30f}, mx[3] = {-1e30f, -1e30f, -1e30f};
        for (int v = 0; v < 8; v++)
            for (int d = 0; d < 3; d++) {
                float t = p[v * 3 + d];
                mn[d] = fminf(mn[d], t);
                mx[d] = fmaxf(mx[d], t);
            }
        for (int d = 0; d < 3; d++) sizes[(b * Nn + n) * 3 + d] = mx[d] - mn[d];
    } else if (blk < 8224) {  // ---- head weights ----
        int b = blk - 8208, c = tid;
        float s = 0.0f;
        for (int t = 0; t < Tn; t++) s += lang[((size_t)b * Tn + t) * Cn + c];
        sm0[c] = s * (1.0f / Tn);
        __syncthreads();
        float acc = bt1[c];
        for (int i = 0; i < Cn; i++) acc += sm0[i] * Wt1[i * Cn + c];
        sm1[c] = gelu_exact(acc);
        __syncthreads();
        if (c < Hn) {
            float a = bt2[c];
            for (int i = 0; i < Cn; i++) a += sm1[i] * Wt2[i * Hn + c];
            headw[b * Hn + c] = 1.0f / (1.0f + expf(-a));
        }
    } else if (blk < 8272) {  // ---- W_qkv^T -> bf16 [768 o][256 k] (48 tiles) ----
        int t = blk - 8224;
        int kt = t & 3, ot = t >> 2;
        for (int itr = 0; itr < 16; itr++) {
            int idx = itr * 256 + tid;
            int r = idx >> 6, c = idx & 63;
            T[r][c] = W_qkv[(size_t)(kt * 64 + r) * 768 + ot * 64 + c];
        }
        __syncthreads();
        for (int itr = 0; itr < 16; itr++) {
            int idx = itr * 256 + tid;
            int r = idx >> 6, c = idx & 63;  // r=o-local, c=k-local
            wqT[(size_t)(ot * 64 + r) * 256 + kt * 64 + c] = (__bf16)T[c][r];
        }
    } else {  // ---- W_proj^T -> bf16 [256 o][256 k] (16 tiles) ----
        int t = blk - 8272;
        int kt = t & 3, ot = t >> 2;
        for (int itr = 0; itr < 16; itr++) {
            int idx = itr * 256 + tid;
            int r = idx >> 6, c = idx & 63;
            T[r][c] = W_proj[(size_t)(kt * 64 + r) * 256 + ot * 64 + c];
        }
        __syncthreads();
        for (int itr = 0; itr < 16; itr++) {
            int idx = itr * 256 + tid;
            int r = idx >> 6, c = idx & 63;
            wpT[(size_t)(ot * 64 + r) * 256 + kt * 64 + c] = (__bf16)T[c][r];
        }
    }
}

// ---------------- pairwise geometry bias MLP (as r4, LDS shrunk) ----------------
__global__ void __launch_bounds__(256) k_geombias(
    const float* __restrict__ centers, const float* __restrict__ sizes,
    const float* __restrict__ Wg1, const float* __restrict__ bg1,
    const float* __restrict__ Wg2, const float* __restrict__ bg2,
    const float* __restrict__ headw, const float* __restrict__ alphap,
    float* __restrict__ bias_eff) {
    __shared__ __bf16 fT[Nn][16];       // [j][k]   8 KB
    __shared__ __bf16 W1T[Cn][16];      // [c][k]   8 KB
    __shared__ __bf16 W2T[4][264];      // [h][c]   2.06 KB
    __shared__ __bf16 gbuf[4][64][40];  // per-wave 20 KB

    int bi = blockIdx.x;
    int b = bi >> 8, i = bi & 255;
    int tid = threadIdx.x;

    {
        int c = tid;
        __bf16 t1[16];
#pragma unroll
        for (int k = 0; k < 12; k++) t1[k] = (__bf16)Wg1[k * Cn + c];
        t1[12] = (__bf16)bg1[c];
#pragma unroll
        for (int k = 13; k < 16; k++) t1[k] = (__bf16)0.f;
        *(bf16x8*)&W1T[c][0] = *(bf16x8*)&t1[0];
        *(bf16x8*)&W1T[c][8] = *(bf16x8*)&t1[8];
#pragma unroll
        for (int h = 0; h < Hn; h++) W2T[h][c] = (__bf16)Wg2[c * Hn + h];
    }
    {
        int j = tid;
        float ci0 = centers[(b * Nn + i) * 3 + 0];
        float ci1 = centers[(b * Nn + i) * 3 + 1];
        float ci2 = centers[(b * Nn + i) * 3 + 2];
        float si0 = sizes[(b * Nn + i) * 3 + 0];
        float si1 = sizes[(b * Nn + i) * 3 + 1];
        float si2 = sizes[(b * Nn + i) * 3 + 2];
        float cj0 = centers[(b * Nn + j) * 3 + 0];
        float cj1 = centers[(b * Nn + j) * 3 + 1];
        float cj2 = centers[(b * Nn + j) * 3 + 2];
        float sj0 = sizes[(b * Nn + j) * 3 + 0];
        float sj1 = sizes[(b * Nn + j) * 3 + 1];
        float sj2 = sizes[(b * Nn + j) * 3 + 2];
        float rx = cj0 - ci0, ry = cj1 - ci1, rz = cj2 - ci2;
        float h2 = rx * rx + ry * ry;
        float dist = sqrtf(h2 + rz * rz);
        float horiz = sqrtf(h2);
        float f[16];
        f[0] = rx; f[1] = ry; f[2] = rz;
        f[3] = dist; f[4] = horiz;
        f[5] = rz / (dist + 1e-6f);
        f[6] = sj0 - si0; f[7] = sj1 - si1; f[8] = sj2 - si2;
        f[9] = sj0 / (si0 + 1e-6f);
        f[10] = sj1 / (si1 + 1e-6f);
        f[11] = sj2 / (si2 + 1e-6f);
        f[12] = 1.0f;
        __bf16 tf[16];
#pragma unroll
        for (int k = 0; k < 13; k++) tf[k] = (__bf16)f[k];
#pragma unroll
        for (int k = 13; k < 16; k++) tf[k] = (__bf16)0.f;
        *(bf16x8*)&fT[j][0] = *(bf16x8*)&tf[0];
        *(bf16x8*)&fT[j][8] = *(bf16x8*)&tf[8];
    }
    __syncthreads();

    int w = tid >> 6, l = tid & 63;
    int lr = l & 15, lg = l >> 4;
    int jw = w * 64;
    bool hasK = (l < 32);

    bf16x8 zf;
#pragma unroll
    for (int e = 0; e < 8; e++) zf[e] = (__bf16)0.f;
    f32x4 zero4 = {0.f, 0.f, 0.f, 0.f};

    bf16x8 bf_[4];
#pragma unroll
    for (int jt = 0; jt < 4; jt++)
        bf_[jt] = hasK ? *(const bf16x8*)&fT[jw + jt * 16 + lr][lg * 8] : zf;

    f32x4 pacc[4];
#pragma unroll
    for (int jt = 0; jt < 4; jt++) pacc[jt] = zero4;

    for (int cc = 0; cc < 8; cc++) {
#pragma unroll
        for (int ct = 0; ct < 2; ct++) {
            int cbase = cc * 32 + ct * 16;
            bf16x8 aw = hasK ? *(const bf16x8*)&W1T[cbase + lr][lg * 8] : zf;
#pragma unroll
            for (int jt = 0; jt < 4; jt++) {
                f32x4 acc = MFMA16(aw, bf_[jt], zero4);
                __bf16 gv[4];
#pragma unroll
                for (int r = 0; r < 4; r++) gv[r] = (__bf16)gelu_sig(acc[r]);
                *(uint2*)&gbuf[w][jt * 16 + lr][ct * 16 + lg * 4] = *(uint2*)&gv[0];
            }
        }
        bf16x8 b2 = (lr < Hn) ? *(const bf16x8*)&W2T[lr][cc * 32 + lg * 8] : zf;
#pragma unroll
        for (int jt = 0; jt < 4; jt++) {
            bf16x8 a2 = *(const bf16x8*)&gbuf[w][jt * 16 + lr][lg * 8];
            pacc[jt] = MFMA16(a2, b2, pacc[jt]);
        }
    }

    float alpha = alphap[0];
    if (lr < Hn) {
        float hw_ = headw[b * Hn + lr];
        float bg = bg2[lr];
        float* dst = bias_eff + (((size_t)(b * Hn + lr)) * Nn + i) * Nn;
#pragma unroll
        for (int jt = 0; jt < 4; jt++)
#pragma unroll
            for (int r = 0; r < 4; r++)
                dst[jw + jt * 16 + lg * 4 + r] = alpha * hw_ * (pacc[jt][r] + bg);
    }
}

// ---------------- QKV projection: MFMA, frags straight from global (L2) ----------------
// grid (64, 12): x = 64-row block, y = 64-col tile (y>>2 = q/k/v, y&3 = head)
__global__ void __launch_bounds__(256) k_qkv(const __bf16* __restrict__ xnb,
                                             const __bf16* __restrict__ wqT,
                                             const float* __restrict__ bqkv,
                                             __bf16* __restrict__ qkvb) {
    int ib = blockIdx.x, y = blockIdx.y;
    int tid = threadIdx.x;
    int w = tid >> 6, l = tid & 63, lr = l & 15, lg = l >> 4;
    const __bf16* arow = xnb + (size_t)(ib * 64 + w * 16 + lr) * Cn;

    f32x4 acc[4];
#pragma unroll
    for (int ot = 0; ot < 4; ot++) acc[ot] = (f32x4){0.f, 0.f, 0.f, 0.f};

#pragma unroll
    for (int kc = 0; kc < 8; kc++) {
        bf16x8 af = *(const bf16x8*)(arow + kc * 32 + lg * 8);
#pragma unroll
        for (int ot = 0; ot < 4; ot++) {
            bf16x8 bfr = *(const bf16x8*)(wqT + (size_t)(y * 64 + ot * 16 + lr) * Cn +
                                          kc * 32 + lg * 8);
            acc[ot] = MFMA16(af, bfr, acc[ot]);
        }
    }

    int seg = y >> 2, h = y & 3;
    __bf16* segp = qkvb + (size_t)seg * 1048576;
#pragma unroll
    for (int ot = 0; ot < 4; ot++) {
        float bo = bqkv[y * 64 + ot * 16 + lr];
#pragma unroll
        for (int r = 0; r < 4; r++) {
            int ig = ib * 64 + w * 16 + lg * 4 + r;
            int b = ig >> 8, n = ig & 255;
            segp[(((size_t)(b * Hn + h)) * Nn + n) * HDn + ot * 16 + lr] =
                (__bf16)(acc[ot][r] + bo);
        }
    }
}

// ---------------- attention: MFMA flash-style, 64 i-rows per block ----------------
// grid 256: blk>>2 = bh, blk&3 = it (64-row slab). Wave w owns 16 i-rows.
__global__ void __launch_bounds__(256) k_attn(const __bf16* __restrict__ qkvb,
                                              const float* __restrict__ bias_eff,
                                              const unsigned char* __restrict__ knn,
                                              float* __restrict__ attn_out,
                                              __bf16* __restrict__ houtb) {
    __shared__ __bf16 Vt[64][264];        // V^T [d][j]  33.8 KB
    __shared__ __bf16 Plds[4][16][136];   // per-wave P half-slab 17.4 KB
    int blk = blockIdx.x;
    int bh = blk >> 2, it = blk & 3;
    int b = bh >> 2, h = bh & 3;
    int tid = threadIdx.x;

    const __bf16* vbase = qkvb + 2 * 1048576 + (size_t)bh * (Nn * HDn);
    {
        int j = tid;
#pragma unroll
        for (int c8 = 0; c8 < 8; c8++) {
            bf16x8 v8 = *(const bf16x8*)(vbase + (size_t)j * HDn + c8 * 8);
#pragma unroll
            for (int e = 0; e < 8; e++) Vt[c8 * 8 + e][j] = v8[e];
        }
    }
    __syncthreads();

    int w = tid >> 6, l = tid & 63;
    int lr = l & 15, lg = l >> 4;
    int i_glob = it * 64 + w * 16 + lr;

    // Q B-frags (col i = lr)
    const __bf16* qrow = qkvb + (size_t)bh * (Nn * HDn) + (size_t)i_glob * HDn;
    bf16x8 qf0 = *(const bf16x8*)(qrow + lg * 8);
    bf16x8 qf1 = *(const bf16x8*)(qrow + 32 + lg * 8);

    // QK^T: A = K rows j
    const __bf16* kbase = qkvb + 1048576 + (size_t)bh * (Nn * HDn);
    f32x4 s[16];
#pragma unroll
    for (int jt = 0; jt < 16; jt++) {
        const __bf16* krow = kbase + (size_t)(jt * 16 + lr) * HDn;
        bf16x8 ka = *(const bf16x8*)(krow + lg * 8);
        bf16x8 kb = *(const bf16x8*)(krow + 32 + lg * 8);
        f32x4 acc = (f32x4){0.f, 0.f, 0.f, 0.f};
        acc = MFMA16(ka, qf0, acc);
        acc = MFMA16(kb, qf1, acc);
        s[jt] = acc;  // rows j = jt*16 + lg*4 + r, col i = lr
    }

    // bias + mask + softmax (row i = lr is lane-local over j)
    const float* brow = bias_eff + ((size_t)bh * Nn + i_glob) * Nn;
    const unsigned int* mrow = (const unsigned int*)(knn + ((size_t)(b * Nn + i_glob)) * Nn);
    float mx = -1e30f;
#pragma unroll
    for (int jt = 0; jt < 16; jt++) {
        f32x4 bi = *(const f32x4*)(brow + jt * 16 + lg * 4);
        unsigned int mk = mrow[jt * 4 + lg];
#pragma unroll
        for (int r = 0; r < 4; r++) {
            float v = fmaf(s[jt][r], 0.125f, bi[r]);
            v = ((mk >> (8 * r)) & 0xff) ? v : -1e9f;
            s[jt][r] = v;
            mx = fmaxf(mx, v);
        }
    }
    mx = fmaxf(mx, __shfl_xor(mx, 16, 64));
    mx = fmaxf(mx, __shfl_xor(mx, 32, 64));
    float sum = 0.0f;
#pragma unroll
    for (int jt = 0; jt < 16; jt++)
#pragma unroll
        for (int r = 0; r < 4; r++) {
            float e = __builtin_amdgcn_exp2f((s[jt][r] - mx) * 1.44269504f);
            s[jt][r] = e;
            sum += e;
        }
    sum += __shfl_xor(sum, 16, 64);
    sum += __shfl_xor(sum, 32, 64);
    float inv = 1.0f / sum;

    float* arow = attn_out + ((size_t)bh * Nn + i_glob) * Nn;
#pragma unroll
    for (int jt = 0; jt < 16; jt++) {
        f32x4 o4;
#pragma unroll
        for (int r = 0; r < 4; r++) {
            float a = s[jt][r] * inv;
            s[jt][r] = a;
            o4[r] = a;
        }
        *(f32x4*)(arow + jt * 16 + lg * 4) = o4;
    }

    // PV in two j-halves: P -> per-wave LDS slab -> B-frags; A = Vt
    f32x4 o[4];
#pragma unroll
    for (int dt = 0; dt < 4; dt++) o[dt] = (f32x4){0.f, 0.f, 0.f, 0.f};
    for (int half = 0; half < 2; half++) {
#pragma unroll
        for (int jr = 0; jr < 8; jr++) {
            int jt = half * 8 + jr;
            __bf16 pb[4];
#pragma unroll
            for (int r = 0; r < 4; r++) pb[r] = (__bf16)s[jt][r];
            *(uint2*)&Plds[w][lr][jr * 16 + lg * 4] = *(uint2*)pb;
        }
#pragma unroll
        for (int kk = 0; kk < 4; kk++) {
            bf16x8 pfrag = *(const bf16x8*)&Plds[w][lr][kk * 32 + lg * 8];
#pragma unroll
            for (int dt = 0; dt < 4; dt++) {
                bf16x8 vfrag = *(const bf16x8*)&Vt[dt * 16 + lr][half * 128 + kk * 32 + lg * 8];
                o[dt] = MFMA16(vfrag, pfrag, o[dt]);
            }
        }
    }

    // store O (bf16): col i = lr, rows d = dt*16 + lg*4 + r
    __bf16* hrow = houtb + ((size_t)(b * Nn + i_glob)) * Cn + h * HDn;
#pragma unroll
    for (int dt = 0; dt < 4; dt++) {
        __bf16 hb[4];
#pragma unroll
        for (int r = 0; r < 4; r++) hb[r] = (__bf16)o[dt][r];
        *(uint2*)(hrow + dt * 16 + lg * 4) = *(uint2*)hb;
    }
}

// ---------------- output projection + residual: MFMA ----------------
// grid (64, 4)
__global__ void __launch_bounds__(256) k_proj(const __bf16* __restrict__ houtb,
                                              const __bf16* __restrict__ wpT,
                                              const float* __restrict__ bp,
                                              const float* __restrict__ x,
                                              float* __restrict__ xout) {
    int ib = blockIdx.x, y = blockIdx.y;
    int tid = threadIdx.x;
    int w = tid >> 6, l = tid & 63, lr = l & 15, lg = l >> 4;
    const __bf16* arow = houtb + (size_t)(ib * 64 + w * 16 + lr) * Cn;

    f32x4 acc[4];
#pragma unroll
    for (int ot = 0; ot < 4; ot++) acc[ot] = (f32x4){0.f, 0.f, 0.f, 0.f};

#pragma unroll
    for (int kc = 0; kc < 8; kc++) {
        bf16x8 af = *(const bf16x8*)(arow + kc * 32 + lg * 8);
#pragma unroll
        for (int ot = 0; ot < 4; ot++) {
            bf16x8 bfr = *(const bf16x8*)(wpT + (size_t)(y * 64 + ot * 16 + lr) * Cn +
                                          kc * 32 + lg * 8);
            acc[ot] = MFMA16(af, bfr, acc[ot]);
        }
    }

#pragma unroll
    for (int ot = 0; ot < 4; ot++) {
        int o = y * 64 + ot * 16 + lr;
        float bo = bp[o];
#pragma unroll
        for (int r = 0; r < 4; r++) {
            int ig = ib * 64 + w * 16 + lg * 4 + r;
            size_t idx = (size_t)ig * Cn + o;
            xout[idx] = x[idx] + bo + acc[ot][r];
        }
    }
}

extern "C" void kernel_launch(void* const* d_in, const int* in_sizes, int n_in,
                              void* d_out, int out_size, void* d_ws, size_t ws_size,
                              hipStream_t stream) {
    const float* x       = (const float*)d_in[0];
    const float* lang    = (const float*)d_in[1];
    const float* centers = (const float*)d_in[2];
    const float* corners = (const float*)d_in[3];
    const int*   obj     = (const int*)d_in[4];
    const float* ln_g    = (const float*)d_in[5];
    const float* ln_b    = (const float*)d_in[6];
    const float* W_qkv   = (const float*)d_in[7];
    const float* b_qkv   = (const float*)d_in[8];
    const float* W_proj  = (const float*)d_in[9];
    const float* b_proj  = (const float*)d_in[10];
    const float* Wg1     = (const float*)d_in[11];
    const float* bg1     = (const float*)d_in[12];
    const float* Wg2     = (const float*)d_in[13];
    const float* bg2     = (const float*)d_in[14];
    const float* Wt1     = (const float*)d_in[15];
    const float* bt1     = (const float*)d_in[16];
    const float* Wt2     = (const float*)d_in[17];
    const float* bt2     = (const float*)d_in[18];
    const float* alpha   = (const float*)d_in[19];

    float* out = (float*)d_out;
    float* xout     = out;                 // BL*N*C
    float* attn     = out + 1048576;       // BL*H*N*N
    float* bias_eff = out + 5242880;       // BL*H*N*N

    __bf16* xnb   = (__bf16*)d_ws;              // 1,048,576 bf16
    __bf16* qkvb  = xnb + 1048576;              // 3 x 1,048,576 bf16 (q,k,v)
    __bf16* houtb = qkvb + 3145728;             // 1,048,576 bf16
    __bf16* wqT   = houtb + 1048576;            // 196,608 bf16
    __bf16* wpT   = wqT + 196608;               // 65,536 bf16
    float*  sizes = (float*)(wpT + 65536);      // 12,288 f32
    float*  headw = sizes + 12288;              // 64 f32
    unsigned char* knn = (unsigned char*)(headw + 64);  // 1 MiB

    k_prep<<<8288, 256, 0, stream>>>(x, ln_g, ln_b, xnb, centers, obj, knn, corners, sizes,
                                     lang, Wt1, bt1, Wt2, bt2, headw, W_qkv, wqT, W_proj, wpT);
    k_geombias<<<BLn * Nn, Nn, 0, stream>>>(centers, sizes, Wg1, bg1, Wg2, bg2, headw, alpha,
                                            bias_eff);
    k_qkv<<<dim3(64, 12), 256, 0, stream>>>(xnb, wqT, b_qkv, qkvb);
    k_attn<<<256, 256, 0, stream>>>(qkvb, bias_eff, knn, attn, houtb);
    k_proj<<<dim3(64, 4), 256, 0, stream>>>(houtb, wpT, b_proj, x, xout);
}

// Round 6
// 144.767 us; speedup vs baseline: 4.1258x; 1.1288x over previous
//
#include <hip/hip_runtime.h>
#include <math.h>

#define BLn 16
#define Nn 256
#define Tn 32
#define Cn 256
#define Hn 4
#define HDn 64
#define KREL 32

typedef float f32x4 __attribute__((ext_vector_type(4)));
typedef __bf16 bf16x8 __attribute__((ext_vector_type(8)));

#define MFMA16(a, b, c) __builtin_amdgcn_mfma_f32_16x16x32_bf16(a, b, c, 0, 0, 0)

union frag_u {
    bf16x8 v;
    uint2 u[2];
};

__device__ __forceinline__ float gelu_exact(float x) {
    return 0.5f * x * (1.0f + erff(x * 0.70710678118654752440f));
}

// sigmoid-form gelu (validated r4/r5)
__device__ __forceinline__ float gelu_sig(float x) {
    float e = __builtin_amdgcn_exp2f(-2.4554669f * x);
    return x * __builtin_amdgcn_rcpf(1.0f + e);
}

// ---------------- fused prep: ln | knn | sizes | headw | W transposes ----------------
__global__ void __launch_bounds__(256) k_prep(
    const float* __restrict__ x, const float* __restrict__ ln_g, const float* __restrict__ ln_b,
    __bf16* __restrict__ xnb, const float* __restrict__ centers, const int* __restrict__ obj,
    unsigned char* __restrict__ knn, const float* __restrict__ corners,
    float* __restrict__ sizes, const float* __restrict__ lang, const float* __restrict__ Wt1,
    const float* __restrict__ bt1, const float* __restrict__ Wt2, const float* __restrict__ bt2,
    float* __restrict__ headw, const float* __restrict__ W_qkv, __bf16* __restrict__ wqT,
    const float* __restrict__ W_proj, __bf16* __restrict__ wpT) {
    __shared__ float4 d4[64];
    __shared__ float sm1[Nn];
    __shared__ float ss[4], qq[4];
    __shared__ float T[64][65];
    float* sm0 = (float*)d4;
    int blk = blockIdx.x;
    int tid = threadIdx.x;

    if (blk < 4096) {  // ---- LayerNorm -> bf16 ----
        int row = blk;
        int c = tid;
        float v = x[(size_t)row * Cn + c];
        float s = v, q = v * v;
        for (int m = 32; m > 0; m >>= 1) {
            s += __shfl_xor(s, m, 64);
            q += __shfl_xor(q, m, 64);
        }
        int w = c >> 6, l = c & 63;
        if (l == 0) { ss[w] = s; qq[w] = q; }
        __syncthreads();
        s = ss[0] + ss[1] + ss[2] + ss[3];
        q = qq[0] + qq[1] + qq[2] + qq[3];
        float mu = s * (1.0f / Cn);
        float var = q * (1.0f / Cn) - mu * mu;
        float r = rsqrtf(var + 1e-5f);
        xnb[(size_t)row * Cn + c] = (__bf16)((v - mu) * r * ln_g[c] + ln_b[c]);
    } else if (blk < 8192) {  // ---- KNN + pair mask ----
        int bi = blk - 4096;
        int b = bi >> 8, i = bi & 255;
        int j = tid;
        float cx = centers[(b * Nn + i) * 3 + 0];
        float cy = centers[(b * Nn + i) * 3 + 1];
        float cz = centers[(b * Nn + i) * 3 + 2];
        float dx = centers[(b * Nn + j) * 3 + 0] - cx;
        float dy = centers[(b * Nn + j) * 3 + 1] - cy;
        float dz = centers[(b * Nn + j) * 3 + 2] - cz;
        float dd = sqrtf(dx * dx + dy * dy + dz * dz);
        sm0[j] = dd;
        __syncthreads();
        int rank = 0;
        for (int t4 = 0; t4 < 64; t4++) {
            float4 o = d4[t4];
            int t = t4 * 4;
            rank += (o.x < dd) || (o.x == dd && t + 0 < j);
            rank += (o.y < dd) || (o.y == dd && t + 1 < j);
            rank += (o.z < dd) || (o.z == dd && t + 2 < j);
            rank += (o.w < dd) || (o.w == dd && t + 3 < j);
        }
        bool m = (rank < KREL);
        m = m && (obj[b * Nn + i] != 0) && (obj[b * Nn + j] != 0);
        knn[(size_t)bi * Nn + j] = m ? 1 : 0;
    } else if (blk < 8208) {  // ---- sizes ----
        int b = blk - 8192, n = tid;
        const float* p = corners + (size_t)((b * Nn + n) * 8) * 3;
        float mn[3] = {1e30f, 1e30f, 1e30f}, mx[3] = {-1e30f, -1e30f, -1e30f};
        for (int v = 0; v < 8; v++)
            for (int d = 0; d < 3; d++) {
                float t = p[v * 3 + d];
                mn[d] = fminf(mn[d], t);
                mx[d] = fmaxf(mx[d], t);
            }
        for (int d = 0; d < 3; d++) sizes[(b * Nn + n) * 3 + d] = mx[d] - mn[d];
    } else if (blk < 8224) {  // ---- head weights ----
        int b = blk - 8208, c = tid;
        float s = 0.0f;
        for (int t = 0; t < Tn; t++) s += lang[((size_t)b * Tn + t) * Cn + c];
        sm0[c] = s * (1.0f / Tn);
        __syncthreads();
        float acc = bt1[c];
        for (int i = 0; i < Cn; i++) acc += sm0[i] * Wt1[i * Cn + c];
        sm1[c] = gelu_exact(acc);
        __syncthreads();
        if (c < Hn) {
            float a = bt2[c];
            for (int i = 0; i < Cn; i++) a += sm1[i] * Wt2[i * Hn + c];
            headw[b * Hn + c] = 1.0f / (1.0f + expf(-a));
        }
    } else if (blk < 8272) {  // ---- W_qkv^T -> bf16 [768 o][256 k] ----
        int t = blk - 8224;
        int kt = t & 3, ot = t >> 2;
        for (int itr = 0; itr < 16; itr++) {
            int idx = itr * 256 + tid;
            int r = idx >> 6, c = idx & 63;
            T[r][c] = W_qkv[(size_t)(kt * 64 + r) * 768 + ot * 64 + c];
        }
        __syncthreads();
        for (int itr = 0; itr < 16; itr++) {
            int idx = itr * 256 + tid;
            int r = idx >> 6, c = idx & 63;
            wqT[(size_t)(ot * 64 + r) * 256 + kt * 64 + c] = (__bf16)T[c][r];
        }
    } else {  // ---- W_proj^T -> bf16 [256 o][256 k] ----
        int t = blk - 8272;
        int kt = t & 3, ot = t >> 2;
        for (int itr = 0; itr < 16; itr++) {
            int idx = itr * 256 + tid;
            int r = idx >> 6, c = idx & 63;
            T[r][c] = W_proj[(size_t)(kt * 64 + r) * 256 + ot * 64 + c];
        }
        __syncthreads();
        for (int itr = 0; itr < 16; itr++) {
            int idx = itr * 256 + tid;
            int r = idx >> 6, c = idx & 63;
            wpT[(size_t)(ot * 64 + r) * 256 + kt * 64 + c] = (__bf16)T[c][r];
        }
    }
}

// ---------------- fused heavy kernel: geombias (blocks 0..4095) + qkv (4096..4863) ----
__global__ void __launch_bounds__(256, 5) k_heavy(
    const float* __restrict__ centers, const float* __restrict__ sizes,
    const float* __restrict__ Wg1, const float* __restrict__ bg1,
    const float* __restrict__ Wg2, const float* __restrict__ bg2,
    const float* __restrict__ headw, const float* __restrict__ alphap,
    float* __restrict__ bias_eff, const __bf16* __restrict__ xnb,
    const __bf16* __restrict__ wqT, const float* __restrict__ bqkv,
    __bf16* __restrict__ qkvb) {
    __shared__ __bf16 fT[Nn][16];       // [j][k]             8192 B
    __shared__ __bf16 W1T[257][20];     // [c][k] pad row    10280 B
    __shared__ __bf16 W2T[4][260];      // [h][c]             2080 B
    __shared__ __bf16 gbuf[4][32][40];  // per-wave          10240 B

    int blk = blockIdx.x;
    int tid = threadIdx.x;

    if (blk >= 4096) {
        // ================= QKV path =================
        int t = blk - 4096;
        int ib = t & 63, y = t >> 6;
        int w = tid >> 6, l = tid & 63, lr = l & 15, lg = l >> 4;
        const __bf16* arow = xnb + (size_t)(ib * 64 + w * 16 + lr) * Cn;

        f32x4 acc[4];
#pragma unroll
        for (int ot = 0; ot < 4; ot++) acc[ot] = (f32x4){0.f, 0.f, 0.f, 0.f};
#pragma unroll
        for (int kc = 0; kc < 8; kc++) {
            bf16x8 af = *(const bf16x8*)(arow + kc * 32 + lg * 8);
#pragma unroll
            for (int ot = 0; ot < 4; ot++) {
                bf16x8 bfr = *(const bf16x8*)(wqT + (size_t)(y * 64 + ot * 16 + lr) * Cn +
                                              kc * 32 + lg * 8);
                acc[ot] = MFMA16(af, bfr, acc[ot]);
            }
        }
        int seg = y >> 2, h = y & 3;
        __bf16* segp = qkvb + (size_t)seg * 1048576;
#pragma unroll
        for (int ot = 0; ot < 4; ot++) {
            float bo = bqkv[y * 64 + ot * 16 + lr];
#pragma unroll
            for (int r = 0; r < 4; r++) {
                int ig = ib * 64 + w * 16 + lg * 4 + r;
                int b = ig >> 8, n = ig & 255;
                segp[(((size_t)(b * Hn + h)) * Nn + n) * HDn + ot * 16 + lr] =
                    (__bf16)(acc[ot][r] + bo);
            }
        }
        return;
    }

    // ================= geombias path =================
    int b = blk >> 8, i = blk & 255;

    // ---- stage weights (thread = c) ----
    {
        int c = tid;
        __bf16 t1[20];
#pragma unroll
        for (int k = 0; k < 12; k++) t1[k] = (__bf16)Wg1[k * Cn + c];
        t1[12] = (__bf16)bg1[c];
#pragma unroll
        for (int k = 13; k < 20; k++) t1[k] = (__bf16)0.f;
#pragma unroll
        for (int q = 0; q < 5; q++) *(uint2*)&W1T[c][q * 4] = *(uint2*)&t1[q * 4];
#pragma unroll
        for (int h = 0; h < Hn; h++) W2T[h][c] = (__bf16)Wg2[c * Hn + h];
    }
    // ---- features for pair (i, j=tid) ----
    {
        int j = tid;
        float ci0 = centers[(b * Nn + i) * 3 + 0];
        float ci1 = centers[(b * Nn + i) * 3 + 1];
        float ci2 = centers[(b * Nn + i) * 3 + 2];
        float si0 = sizes[(b * Nn + i) * 3 + 0];
        float si1 = sizes[(b * Nn + i) * 3 + 1];
        float si2 = sizes[(b * Nn + i) * 3 + 2];
        float cj0 = centers[(b * Nn + j) * 3 + 0];
        float cj1 = centers[(b * Nn + j) * 3 + 1];
        float cj2 = centers[(b * Nn + j) * 3 + 2];
        float sj0 = sizes[(b * Nn + j) * 3 + 0];
        float sj1 = sizes[(b * Nn + j) * 3 + 1];
        float sj2 = sizes[(b * Nn + j) * 3 + 2];
        float rx = cj0 - ci0, ry = cj1 - ci1, rz = cj2 - ci2;
        float h2 = rx * rx + ry * ry;
        float dist = sqrtf(h2 + rz * rz);
        float horiz = sqrtf(h2);
        float f[16];
        f[0] = rx; f[1] = ry; f[2] = rz;
        f[3] = dist; f[4] = horiz;
        f[5] = rz / (dist + 1e-6f);
        f[6] = sj0 - si0; f[7] = sj1 - si1; f[8] = sj2 - si2;
        f[9] = sj0 / (si0 + 1e-6f);
        f[10] = sj1 / (si1 + 1e-6f);
        f[11] = sj2 / (si2 + 1e-6f);
        f[12] = 1.0f;
        __bf16 tf[16];
#pragma unroll
        for (int k = 0; k < 13; k++) tf[k] = (__bf16)f[k];
#pragma unroll
        for (int k = 13; k < 16; k++) tf[k] = (__bf16)0.f;
        *(bf16x8*)&fT[j][0] = *(bf16x8*)&tf[0];
        *(bf16x8*)&fT[j][8] = *(bf16x8*)&tf[8];
    }
    __syncthreads();

    int w = tid >> 6, l = tid & 63;
    int lr = l & 15, lg = l >> 4;
    int jw = w * 64;
    int lgc = (lg < 2) ? lg : 1;  // clamped (safe addr), pad lanes get zf
    bool hk = (lg < 2);
    int lrc = (lr < 4) ? lr : 3;
    bool hr = (lr < 4);

    bf16x8 zf;
#pragma unroll
    for (int e = 0; e < 8; e++) zf[e] = (__bf16)0.f;
    f32x4 zero4 = {0.f, 0.f, 0.f, 0.f};

    bf16x8 bf_[4];
#pragma unroll
    for (int jt = 0; jt < 4; jt++) {
        bf16x8 v = *(const bf16x8*)&fT[jw + jt * 16 + lr][lgc * 8];
        bf_[jt] = hk ? v : zf;
    }

    f32x4 pacc[4];
#pragma unroll
    for (int jt = 0; jt < 4; jt++) pacc[jt] = zero4;

    for (int cc = 0; cc < 8; cc++) {
        int cbase = cc * 32;
        bf16x8 aw[2];
#pragma unroll
        for (int ct = 0; ct < 2; ct++) {
            frag_u fu;
            const __bf16* p = &W1T[cbase + ct * 16 + lr][lgc * 8];
            fu.u[0] = *(const uint2*)p;
            fu.u[1] = *(const uint2*)(p + 4);
            aw[ct] = hk ? fu.v : zf;
        }
        frag_u f2;
        {
            const __bf16* p2 = &W2T[lrc][cbase + lg * 8];
            f2.u[0] = *(const uint2*)p2;
            f2.u[1] = *(const uint2*)(p2 + 4);
        }
        bf16x8 b2 = hr ? f2.v : zf;

#pragma unroll
        for (int jp = 0; jp < 2; jp++) {
#pragma unroll
            for (int j2 = 0; j2 < 2; j2++) {
                int jt = jp * 2 + j2;
                f32x4 a0 = MFMA16(aw[0], bf_[jt], zero4);
                f32x4 a1 = MFMA16(aw[1], bf_[jt], zero4);
                __bf16 g0[4], g1[4];
#pragma unroll
                for (int r = 0; r < 4; r++) {
                    g0[r] = (__bf16)gelu_sig(a0[r]);
                    g1[r] = (__bf16)gelu_sig(a1[r]);
                }
                *(uint2*)&gbuf[w][j2 * 16 + lr][lg * 4] = *(uint2*)g0;
                *(uint2*)&gbuf[w][j2 * 16 + lr][16 + lg * 4] = *(uint2*)g1;
            }
#pragma unroll
            for (int j2 = 0; j2 < 2; j2++) {
                int jt = jp * 2 + j2;
                bf16x8 a2 = *(const bf16x8*)&gbuf[w][j2 * 16 + lr][lg * 8];
                pacc[jt] = MFMA16(a2, b2, pacc[jt]);
            }
        }
    }

    float alpha = alphap[0];
    if (hr) {  // D: col(h)=lr, row(j-local)=lg*4+r
        float hw_ = headw[b * Hn + lr];
        float bg = bg2[lr];
        float* dst = bias_eff + (((size_t)(b * Hn + lr)) * Nn + i) * Nn;
#pragma unroll
        for (int jt = 0; jt < 4; jt++) {
            f32x4 o4;
#pragma unroll
            for (int r = 0; r < 4; r++) o4[r] = alpha * hw_ * (pacc[jt][r] + bg);
            *(f32x4*)&dst[jw + jt * 16 + lg * 4] = o4;
        }
    }
}

// ---------------- attention: MFMA flash-style, 64 i-rows per block ----------------
__global__ void __launch_bounds__(256) k_attn(const __bf16* __restrict__ qkvb,
                                              const float* __restrict__ bias_eff,
                                              const unsigned char* __restrict__ knn,
                                              float* __restrict__ attn_out,
                                              __bf16* __restrict__ houtb) {
    __shared__ __bf16 Vt[64][264];
    __shared__ __bf16 Plds[4][16][136];
    int blk = blockIdx.x;
    int bh = blk >> 2, it = blk & 3;
    int b = bh >> 2, h = bh & 3;
    int tid = threadIdx.x;

    const __bf16* vbase = qkvb + 2 * 1048576 + (size_t)bh * (Nn * HDn);
    {
        int j = tid;
#pragma unroll
        for (int c8 = 0; c8 < 8; c8++) {
            bf16x8 v8 = *(const bf16x8*)(vbase + (size_t)j * HDn + c8 * 8);
#pragma unroll
            for (int e = 0; e < 8; e++) Vt[c8 * 8 + e][j] = v8[e];
        }
    }
    __syncthreads();

    int w = tid >> 6, l = tid & 63;
    int lr = l & 15, lg = l >> 4;
    int i_glob = it * 64 + w * 16 + lr;

    const __bf16* qrow = qkvb + (size_t)bh * (Nn * HDn) + (size_t)i_glob * HDn;
    bf16x8 qf0 = *(const bf16x8*)(qrow + lg * 8);
    bf16x8 qf1 = *(const bf16x8*)(qrow + 32 + lg * 8);

    const __bf16* kbase = qkvb + 1048576 + (size_t)bh * (Nn * HDn);
    f32x4 s[16];
#pragma unroll
    for (int jt = 0; jt < 16; jt++) {
        const __bf16* krow = kbase + (size_t)(jt * 16 + lr) * HDn;
        bf16x8 ka = *(const bf16x8*)(krow + lg * 8);
        bf16x8 kb = *(const bf16x8*)(krow + 32 + lg * 8);
        f32x4 acc = (f32x4){0.f, 0.f, 0.f, 0.f};
        acc = MFMA16(ka, qf0, acc);
        acc = MFMA16(kb, qf1, acc);
        s[jt] = acc;
    }

    const float* brow = bias_eff + ((size_t)bh * Nn + i_glob) * Nn;
    const unsigned int* mrow = (const unsigned int*)(knn + ((size_t)(b * Nn + i_glob)) * Nn);
    float mx = -1e30f;
#pragma unroll
    for (int jt = 0; jt < 16; jt++) {
        f32x4 bi = *(const f32x4*)(brow + jt * 16 + lg * 4);
        unsigned int mk = mrow[jt * 4 + lg];
#pragma unroll
        for (int r = 0; r < 4; r++) {
            float v = fmaf(s[jt][r], 0.125f, bi[r]);
            v = ((mk >> (8 * r)) & 0xff) ? v : -1e9f;
            s[jt][r] = v;
            mx = fmaxf(mx, v);
        }
    }
    mx = fmaxf(mx, __shfl_xor(mx, 16, 64));
    mx = fmaxf(mx, __shfl_xor(mx, 32, 64));
    float sum = 0.0f;
#pragma unroll
    for (int jt = 0; jt < 16; jt++)
#pragma unroll
        for (int r = 0; r < 4; r++) {
            float e = __builtin_amdgcn_exp2f((s[jt][r] - mx) * 1.44269504f);
            s[jt][r] = e;
            sum += e;
        }
    sum += __shfl_xor(sum, 16, 64);
    sum += __shfl_xor(sum, 32, 64);
    float inv = 1.0f / sum;

    float* arow = attn_out + ((size_t)bh * Nn + i_glob) * Nn;
#pragma unroll
    for (int jt = 0; jt < 16; jt++) {
        f32x4 o4;
#pragma unroll
        for (int r = 0; r < 4; r++) {
            float a = s[jt][r] * inv;
            s[jt][r] = a;
            o4[r] = a;
        }
        *(f32x4*)(arow + jt * 16 + lg * 4) = o4;
    }

    f32x4 o[4];
#pragma unroll
    for (int dt = 0; dt < 4; dt++) o[dt] = (f32x4){0.f, 0.f, 0.f, 0.f};
    for (int half = 0; half < 2; half++) {
#pragma unroll
        for (int jr = 0; jr < 8; jr++) {
            int jt = half * 8 + jr;
            __bf16 pb[4];
#pragma unroll
            for (int r = 0; r < 4; r++) pb[r] = (__bf16)s[jt][r];
            *(uint2*)&Plds[w][lr][jr * 16 + lg * 4] = *(uint2*)pb;
        }
#pragma unroll
        for (int kk = 0; kk < 4; kk++) {
            bf16x8 pfrag = *(const bf16x8*)&Plds[w][lr][kk * 32 + lg * 8];
#pragma unroll
            for (int dt = 0; dt < 4; dt++) {
                bf16x8 vfrag = *(const bf16x8*)&Vt[dt * 16 + lr][half * 128 + kk * 32 + lg * 8];
                o[dt] = MFMA16(vfrag, pfrag, o[dt]);
            }
        }
    }

    __bf16* hrow = houtb + ((size_t)(b * Nn + i_glob)) * Cn + h * HDn;
#pragma unroll
    for (int dt = 0; dt < 4; dt++) {
        __bf16 hb[4];
#pragma unroll
        for (int r = 0; r < 4; r++) hb[r] = (__bf16)o[dt][r];
        *(uint2*)(hrow + dt * 16 + lg * 4) = *(uint2*)hb;
    }
}

// ---------------- output projection + residual: MFMA ----------------
__global__ void __launch_bounds__(256) k_proj(const __bf16* __restrict__ houtb,
                                              const __bf16* __restrict__ wpT,
                                              const float* __restrict__ bp,
                                              const float* __restrict__ x,
                                              float* __restrict__ xout) {
    int ib = blockIdx.x, y = blockIdx.y;
    int tid = threadIdx.x;
    int w = tid >> 6, l = tid & 63, lr = l & 15, lg = l >> 4;
    const __bf16* arow = houtb + (size_t)(ib * 64 + w * 16 + lr) * Cn;

    f32x4 acc[4];
#pragma unroll
    for (int ot = 0; ot < 4; ot++) acc[ot] = (f32x4){0.f, 0.f, 0.f, 0.f};
#pragma unroll
    for (int kc = 0; kc < 8; kc++) {
        bf16x8 af = *(const bf16x8*)(arow + kc * 32 + lg * 8);
#pragma unroll
        for (int ot = 0; ot < 4; ot++) {
            bf16x8 bfr = *(const bf16x8*)(wpT + (size_t)(y * 64 + ot * 16 + lr) * Cn +
                                          kc * 32 + lg * 8);
            acc[ot] = MFMA16(af, bfr, acc[ot]);
        }
    }
#pragma unroll
    for (int ot = 0; ot < 4; ot++) {
        int o = y * 64 + ot * 16 + lr;
        float bo = bp[o];
#pragma unroll
        for (int r = 0; r < 4; r++) {
            int ig = ib * 64 + w * 16 + lg * 4 + r;
            size_t idx = (size_t)ig * Cn + o;
            xout[idx] = x[idx] + bo + acc[ot][r];
        }
    }
}

extern "C" void kernel_launch(void* const* d_in, const int* in_sizes, int n_in,
                              void* d_out, int out_size, void* d_ws, size_t ws_size,
                              hipStream_t stream) {
    const float* x       = (const float*)d_in[0];
    const float* lang    = (const float*)d_in[1];
    const float* centers = (const float*)d_in[2];
    const float* corners = (const float*)d_in[3];
    const int*   obj     = (const int*)d_in[4];
    const float* ln_g    = (const float*)d_in[5];
    const float* ln_b    = (const float*)d_in[6];
    const float* W_qkv   = (const float*)d_in[7];
    const float* b_qkv   = (const float*)d_in[8];
    const float* W_proj  = (const float*)d_in[9];
    const float* b_proj  = (const float*)d_in[10];
    const float* Wg1     = (const float*)d_in[11];
    const float* bg1     = (const float*)d_in[12];
    const float* Wg2     = (const float*)d_in[13];
    const float* bg2     = (const float*)d_in[14];
    const float* Wt1     = (const float*)d_in[15];
    const float* bt1     = (const float*)d_in[16];
    const float* Wt2     = (const float*)d_in[17];
    const float* bt2     = (const float*)d_in[18];
    const float* alpha   = (const float*)d_in[19];

    float* out = (float*)d_out;
    float* xout     = out;                 // BL*N*C
    float* attn     = out + 1048576;       // BL*H*N*N
    float* bias_eff = out + 5242880;       // BL*H*N*N

    __bf16* xnb   = (__bf16*)d_ws;              // 1,048,576 bf16
    __bf16* qkvb  = xnb + 1048576;              // 3 x 1,048,576 bf16 (q,k,v)
    __bf16* houtb = qkvb + 3145728;             // 1,048,576 bf16
    __bf16* wqT   = houtb + 1048576;            // 196,608 bf16
    __bf16* wpT   = wqT + 196608;               // 65,536 bf16
    float*  sizes = (float*)(wpT + 65536);      // 12,288 f32
    float*  headw = sizes + 12288;              // 64 f32
    unsigned char* knn = (unsigned char*)(headw + 64);  // 1 MiB

    k_prep<<<8288, 256, 0, stream>>>(x, ln_g, ln_b, xnb, centers, obj, knn, corners, sizes,
                                     lang, Wt1, bt1, Wt2, bt2, headw, W_qkv, wqT, W_proj, wpT);
    k_heavy<<<4864, 256, 0, stream>>>(centers, sizes, Wg1, bg1, Wg2, bg2, headw, alpha,
                                      bias_eff, xnb, wqT, b_qkv, qkvb);
    k_attn<<<256, 256, 0, stream>>>(qkvb, bias_eff, knn, attn, houtb);
    k_proj<<<dim3(64, 4), 256, 0, stream>>>(houtb, wpT, b_proj, x, xout);
}

// Round 8
// 121.975 us; speedup vs baseline: 4.8968x; 1.1869x over previous
//
#include <hip/hip_runtime.h>
#include <math.h>

#define BLn 16
#define Nn 256
#define Tn 32
#define Cn 256
#define Hn 4
#define HDn 64
#define KREL 32

typedef float f32x4 __attribute__((ext_vector_type(4)));
typedef __bf16 bf16x8 __attribute__((ext_vector_type(8)));
typedef _Float16 f16x4 __attribute__((ext_vector_type(4)));
typedef _Float16 f16x2 __attribute__((ext_vector_type(2)));

#define MFMA16(a, b, c) __builtin_amdgcn_mfma_f32_16x16x32_bf16(a, b, c, 0, 0, 0)
#define MFMA16H(a, b, c) __builtin_amdgcn_mfma_f32_16x16x16f16(a, b, c, 0, 0, 0)

__device__ __forceinline__ float gelu_exact(float x) {
    return 0.5f * x * (1.0f + erff(x * 0.70710678118654752440f));
}

// packed-f16 gelu: x*sigma(1.702x), sigma via odd deg-7 poly of tanh(0.851x),
// x clamped to [-4,4], sigma clamped to [0,1]. Max |err| ~0.02 on g ->
// ~3e-4 on bias_eff (256-sum x w2~0.02 x alpha 0.05). No trans ops.
__device__ __forceinline__ f16x2 gelu_pk(f16x2 x) {
    const f16x2 P4 = {(_Float16)4.0f, (_Float16)4.0f};
    const f16x2 M4 = {(_Float16)-4.0f, (_Float16)-4.0f};
    const f16x2 C0 = {(_Float16)0.833076f, (_Float16)0.833076f};
    const f16x2 C1 = {(_Float16)-0.139388f, (_Float16)-0.139388f};
    const f16x2 C2 = {(_Float16)0.013040f, (_Float16)0.013040f};
    const f16x2 C3 = {(_Float16)-0.000413f, (_Float16)-0.000413f};
    const f16x2 HF = {(_Float16)0.5f, (_Float16)0.5f};
    const f16x2 ONE = {(_Float16)1.0f, (_Float16)1.0f};
    const f16x2 ZERO = {(_Float16)0.0f, (_Float16)0.0f};
    f16x2 xc = __builtin_elementwise_min(__builtin_elementwise_max(x, M4), P4);
    f16x2 v = xc * xc;
    f16x2 w = C3 * v + C2;
    w = w * v + C1;
    w = w * v + C0;
    f16x2 t = w * xc;
    f16x2 s = t * HF + HF;
    s = __builtin_elementwise_min(__builtin_elementwise_max(s, ZERO), ONE);
    return x * s;
}

// ---------------- fused prep: ln | knn | sizes | headw | W transposes ----------------
__global__ void __launch_bounds__(256) k_prep(
    const float* __restrict__ x, const float* __restrict__ ln_g, const float* __restrict__ ln_b,
    __bf16* __restrict__ xnb, const float* __restrict__ centers, const int* __restrict__ obj,
    unsigned char* __restrict__ knn, const float* __restrict__ corners,
    float* __restrict__ sizes, const float* __restrict__ lang, const float* __restrict__ Wt1,
    const float* __restrict__ bt1, const float* __restrict__ Wt2, const float* __restrict__ bt2,
    float* __restrict__ headw, const float* __restrict__ W_qkv, __bf16* __restrict__ wqT,
    const float* __restrict__ W_proj, __bf16* __restrict__ wpT) {
    __shared__ float4 d4[64];
    __shared__ float sm1[Nn];
    __shared__ float ss[4], qq[4];
    __shared__ float T[64][65];
    float* sm0 = (float*)d4;
    int blk = blockIdx.x;
    int tid = threadIdx.x;

    if (blk < 4096) {  // ---- LayerNorm -> bf16 ----
        int row = blk;
        int c = tid;
        float v = x[(size_t)row * Cn + c];
        float s = v, q = v * v;
        for (int m = 32; m > 0; m >>= 1) {
            s += __shfl_xor(s, m, 64);
            q += __shfl_xor(q, m, 64);
        }
        int w = c >> 6, l = c & 63;
        if (l == 0) { ss[w] = s; qq[w] = q; }
        __syncthreads();
        s = ss[0] + ss[1] + ss[2] + ss[3];
        q = qq[0] + qq[1] + qq[2] + qq[3];
        float mu = s * (1.0f / Cn);
        float var = q * (1.0f / Cn) - mu * mu;
        float r = rsqrtf(var + 1e-5f);
        xnb[(size_t)row * Cn + c] = (__bf16)((v - mu) * r * ln_g[c] + ln_b[c]);
    } else if (blk < 8192) {  // ---- KNN + pair mask ----
        int bi = blk - 4096;
        int b = bi >> 8, i = bi & 255;
        int j = tid;
        float cx = centers[(b * Nn + i) * 3 + 0];
        float cy = centers[(b * Nn + i) * 3 + 1];
        float cz = centers[(b * Nn + i) * 3 + 2];
        float dx = centers[(b * Nn + j) * 3 + 0] - cx;
        float dy = centers[(b * Nn + j) * 3 + 1] - cy;
        float dz = centers[(b * Nn + j) * 3 + 2] - cz;
        float dd = sqrtf(dx * dx + dy * dy + dz * dz);
        sm0[j] = dd;
        __syncthreads();
        int rank = 0;
        for (int t4 = 0; t4 < 64; t4++) {
            float4 o = d4[t4];
            int t = t4 * 4;
            rank += (o.x < dd) || (o.x == dd && t + 0 < j);
            rank += (o.y < dd) || (o.y == dd && t + 1 < j);
            rank += (o.z < dd) || (o.z == dd && t + 2 < j);
            rank += (o.w < dd) || (o.w == dd && t + 3 < j);
        }
        bool m = (rank < KREL);
        m = m && (obj[b * Nn + i] != 0) && (obj[b * Nn + j] != 0);
        knn[(size_t)bi * Nn + j] = m ? 1 : 0;
    } else if (blk < 8208) {  // ---- sizes ----
        int b = blk - 8192, n = tid;
        const float* p = corners + (size_t)((b * Nn + n) * 8) * 3;
        float mn[3] = {1e30f, 1e30f, 1e30f}, mx[3] = {-1e30f, -1e30f, -1e30f};
        for (int v = 0; v < 8; v++)
            for (int d = 0; d < 3; d++) {
                float t = p[v * 3 + d];
                mn[d] = fminf(mn[d], t);
                mx[d] = fmaxf(mx[d], t);
            }
        for (int d = 0; d < 3; d++) sizes[(b * Nn + n) * 3 + d] = mx[d] - mn[d];
    } else if (blk < 8224) {  // ---- head weights ----
        int b = blk - 8208, c = tid;
        float s = 0.0f;
        for (int t = 0; t < Tn; t++) s += lang[((size_t)b * Tn + t) * Cn + c];
        sm0[c] = s * (1.0f / Tn);
        __syncthreads();
        float acc = bt1[c];
        for (int i = 0; i < Cn; i++) acc += sm0[i] * Wt1[i * Cn + c];
        sm1[c] = gelu_exact(acc);
        __syncthreads();
        if (c < Hn) {
            float a = bt2[c];
            for (int i = 0; i < Cn; i++) a += sm1[i] * Wt2[i * Hn + c];
            headw[b * Hn + c] = 1.0f / (1.0f + expf(-a));
        }
    } else if (blk < 8272) {  // ---- W_qkv^T -> bf16 [768 o][256 k] ----
        int t = blk - 8224;
        int kt = t & 3, ot = t >> 2;
        for (int itr = 0; itr < 16; itr++) {
            int idx = itr * 256 + tid;
            int r = idx >> 6, c = idx & 63;
            T[r][c] = W_qkv[(size_t)(kt * 64 + r) * 768 + ot * 64 + c];
        }
        __syncthreads();
        for (int itr = 0; itr < 16; itr++) {
            int idx = itr * 256 + tid;
            int r = idx >> 6, c = idx & 63;
            wqT[(size_t)(ot * 64 + r) * 256 + kt * 64 + c] = (__bf16)T[c][r];
        }
    } else {  // ---- W_proj^T -> bf16 [256 o][256 k] ----
        int t = blk - 8272;
        int kt = t & 3, ot = t >> 2;
        for (int itr = 0; itr < 16; itr++) {
            int idx = itr * 256 + tid;
            int r = idx >> 6, c = idx & 63;
            T[r][c] = W_proj[(size_t)(kt * 64 + r) * 256 + ot * 64 + c];
        }
        __syncthreads();
        for (int itr = 0; itr < 16; itr++) {
            int idx = itr * 256 + tid;
            int r = idx >> 6, c = idx & 63;
            wpT[(size_t)(ot * 64 + r) * 256 + kt * 64 + c] = (__bf16)T[c][r];
        }
    }
}

// ---------------- fused heavy kernel: geombias (blocks 0..4095) + qkv (4096..4863) ----
// geombias: K=16 f16 MFMA; L1 D-frag == L2 A-frag layout -> gelu entirely in
// registers, NO LDS round-trip. Packed-f16 poly gelu (no trans ops).
__global__ void __launch_bounds__(256, 4) k_heavy(
    const float* __restrict__ centers, const float* __restrict__ sizes,
    const float* __restrict__ Wg1, const float* __restrict__ bg1,
    const float* __restrict__ Wg2, const float* __restrict__ bg2,
    const float* __restrict__ headw, const float* __restrict__ alphap,
    float* __restrict__ bias_eff, const __bf16* __restrict__ xnb,
    const __bf16* __restrict__ wqT, const float* __restrict__ bqkv,
    __bf16* __restrict__ qkvb) {
    __shared__ __align__(16) _Float16 fT[Nn][20];   // [j][k]  10240 B
    __shared__ __align__(16) _Float16 W1T[Cn][20];  // [c][k]  10240 B
    __shared__ __align__(16) _Float16 W2T[16][264]; // [h][c] rows 4..15 zero, 8448 B

    int blk = blockIdx.x;
    int tid = threadIdx.x;

    if (blk >= 4096) {
        // ================= QKV path (bf16 MFMA, K=32) =================
        int t = blk - 4096;
        int ib = t & 63, y = t >> 6;
        int w = tid >> 6, l = tid & 63, lr = l & 15, lg = l >> 4;
        const __bf16* arow = xnb + (size_t)(ib * 64 + w * 16 + lr) * Cn;

        f32x4 acc[4];
#pragma unroll
        for (int ot = 0; ot < 4; ot++) acc[ot] = (f32x4){0.f, 0.f, 0.f, 0.f};
#pragma unroll
        for (int kc = 0; kc < 8; kc++) {
            bf16x8 af = *(const bf16x8*)(arow + kc * 32 + lg * 8);
#pragma unroll
            for (int ot = 0; ot < 4; ot++) {
                bf16x8 bfr = *(const bf16x8*)(wqT + (size_t)(y * 64 + ot * 16 + lr) * Cn +
                                              kc * 32 + lg * 8);
                acc[ot] = MFMA16(af, bfr, acc[ot]);
            }
        }
        int seg = y >> 2, h = y & 3;
        __bf16* segp = qkvb + (size_t)seg * 1048576;
#pragma unroll
        for (int ot = 0; ot < 4; ot++) {
            float bo = bqkv[y * 64 + ot * 16 + lr];
#pragma unroll
            for (int r = 0; r < 4; r++) {
                int ig = ib * 64 + w * 16 + lg * 4 + r;
                int b = ig >> 8, n = ig & 255;
                segp[(((size_t)(b * Hn + h)) * Nn + n) * HDn + ot * 16 + lr] =
                    (__bf16)(acc[ot][r] + bo);
            }
        }
        return;
    }

    // ================= geombias path =================
    int b = blk >> 8, i = blk & 255;

    // ---- stage weights (thread = c) ----
    {
        int c = tid;
        _Float16 t1[20];
#pragma unroll
        for (int k = 0; k < 12; k++) t1[k] = (_Float16)Wg1[k * Cn + c];
        t1[12] = (_Float16)bg1[c];
#pragma unroll
        for (int k = 13; k < 20; k++) t1[k] = (_Float16)0.f;
#pragma unroll
        for (int q = 0; q < 5; q++) *(uint2*)&W1T[c][q * 4] = *(uint2*)&t1[q * 4];
#pragma unroll
        for (int h = 0; h < 16; h++)
            W2T[h][c] = (h < Hn) ? (_Float16)Wg2[c * Hn + h] : (_Float16)0.f;
    }
    // ---- features for pair (i, j=tid) ----
    {
        int j = tid;
        float ci0 = centers[(b * Nn + i) * 3 + 0];
        float ci1 = centers[(b * Nn + i) * 3 + 1];
        float ci2 = centers[(b * Nn + i) * 3 + 2];
        float si0 = sizes[(b * Nn + i) * 3 + 0];
        float si1 = sizes[(b * Nn + i) * 3 + 1];
        float si2 = sizes[(b * Nn + i) * 3 + 2];
        float cj0 = centers[(b * Nn + j) * 3 + 0];
        float cj1 = centers[(b * Nn + j) * 3 + 1];
        float cj2 = centers[(b * Nn + j) * 3 + 2];
        float sj0 = sizes[(b * Nn + j) * 3 + 0];
        float sj1 = sizes[(b * Nn + j) * 3 + 1];
        float sj2 = sizes[(b * Nn + j) * 3 + 2];
        float rx = cj0 - ci0, ry = cj1 - ci1, rz = cj2 - ci2;
        float h2 = rx * rx + ry * ry;
        float dist = sqrtf(h2 + rz * rz);
        float horiz = sqrtf(h2);
        float f[16];
        f[0] = rx; f[1] = ry; f[2] = rz;
        f[3] = dist; f[4] = horiz;
        f[5] = rz / (dist + 1e-6f);
        f[6] = sj0 - si0; f[7] = sj1 - si1; f[8] = sj2 - si2;
        f[9] = sj0 / (si0 + 1e-6f);
        f[10] = sj1 / (si1 + 1e-6f);
        f[11] = sj2 / (si2 + 1e-6f);
        f[12] = 1.0f;  // bias feature -> W1 row 12 = bg1
        _Float16 tf[20];
#pragma unroll
        for (int k = 0; k < 13; k++) tf[k] = (_Float16)f[k];
#pragma unroll
        for (int k = 13; k < 20; k++) tf[k] = (_Float16)0.f;
#pragma unroll
        for (int q = 0; q < 5; q++) *(uint2*)&fT[j][q * 4] = *(uint2*)&tf[q * 4];
    }
    __syncthreads();

    int w = tid >> 6, l = tid & 63;
    int lr = l & 15, lg = l >> 4;
    int jw = w * 64;

    f32x4 zero4 = {0.f, 0.f, 0.f, 0.f};

    // feature B-frags (K=16): lane holds col j = jw+jt*16+lr, k = lg*4+e
    f16x4 bf_[4];
#pragma unroll
    for (int jt = 0; jt < 4; jt++) bf_[jt] = *(const f16x4*)&fT[jw + jt * 16 + lr][lg * 4];

    f32x4 pacc[4];
#pragma unroll
    for (int jt = 0; jt < 4; jt++) pacc[jt] = zero4;

#pragma unroll 2
    for (int cw = 0; cw < 16; cw++) {  // 16 c-windows of K=16
        int cbase = cw * 16;
        // L1 A-frag: row c = cbase+lr, k = lg*4+e
        f16x4 aw = *(const f16x4*)&W1T[cbase + lr][lg * 4];
        // L2 B-frag: k c = cbase+lg*4+e, col h = lr (rows 4..15 of W2T are zero)
        f16x4 b2 = *(const f16x4*)&W2T[lr][cbase + lg * 4];
#pragma unroll
        for (int jt = 0; jt < 4; jt++) {
            // L1: D col j = lr, row c = lg*4+r  == L2 A-frag layout (row j, k c)
            f32x4 acc = MFMA16H(aw, bf_[jt], zero4);
            f16x2 h01 = __builtin_bit_cast(f16x2, __builtin_amdgcn_cvt_pkrtz(acc[0], acc[1]));
            f16x2 h23 = __builtin_bit_cast(f16x2, __builtin_amdgcn_cvt_pkrtz(acc[2], acc[3]));
            h01 = gelu_pk(h01);
            h23 = gelu_pk(h23);
            f16x4 ga;
            ga[0] = h01[0]; ga[1] = h01[1]; ga[2] = h23[0]; ga[3] = h23[1];
            pacc[jt] = MFMA16H(ga, b2, pacc[jt]);
        }
    }

    float alpha = alphap[0];
    if (lr < Hn) {  // D: col(h)=lr, row(j-local)=lg*4+r
        float hw_ = headw[b * Hn + lr];
        float bg = bg2[lr];
        float* dst = bias_eff + (((size_t)(b * Hn + lr)) * Nn + i) * Nn;
#pragma unroll
        for (int jt = 0; jt < 4; jt++) {
            f32x4 o4;
#pragma unroll
            for (int r = 0; r < 4; r++) o4[r] = alpha * hw_ * (pacc[jt][r] + bg);
            *(f32x4*)&dst[jw + jt * 16 + lg * 4] = o4;
        }
    }
}

// ---------------- attention: MFMA flash-style, 64 i-rows per block ----------------
__global__ void __launch_bounds__(256) k_attn(const __bf16* __restrict__ qkvb,
                                              const float* __restrict__ bias_eff,
                                              const unsigned char* __restrict__ knn,
                                              float* __restrict__ attn_out,
                                              __bf16* __restrict__ houtb) {
    __shared__ __bf16 Vt[64][264];
    __shared__ __bf16 Plds[4][16][136];
    int blk = blockIdx.x;
    int bh = blk >> 2, it = blk & 3;
    int b = bh >> 2, h = bh & 3;
    int tid = threadIdx.x;

    const __bf16* vbase = qkvb + 2 * 1048576 + (size_t)bh * (Nn * HDn);
    {
        int j = tid;
#pragma unroll
        for (int c8 = 0; c8 < 8; c8++) {
            bf16x8 v8 = *(const bf16x8*)(vbase + (size_t)j * HDn + c8 * 8);
#pragma unroll
            for (int e = 0; e < 8; e++) Vt[c8 * 8 + e][j] = v8[e];
        }
    }
    __syncthreads();

    int w = tid >> 6, l = tid & 63;
    int lr = l & 15, lg = l >> 4;
    int i_glob = it * 64 + w * 16 + lr;

    const __bf16* qrow = qkvb + (size_t)bh * (Nn * HDn) + (size_t)i_glob * HDn;
    bf16x8 qf0 = *(const bf16x8*)(qrow + lg * 8);
    bf16x8 qf1 = *(const bf16x8*)(qrow + 32 + lg * 8);

    const __bf16* kbase = qkvb + 1048576 + (size_t)bh * (Nn * HDn);
    f32x4 s[16];
#pragma unroll
    for (int jt = 0; jt < 16; jt++) {
        const __bf16* krow = kbase + (size_t)(jt * 16 + lr) * HDn;
        bf16x8 ka = *(const bf16x8*)(krow + lg * 8);
        bf16x8 kb = *(const bf16x8*)(krow + 32 + lg * 8);
        f32x4 acc = (f32x4){0.f, 0.f, 0.f, 0.f};
        acc = MFMA16(ka, qf0, acc);
        acc = MFMA16(kb, qf1, acc);
        s[jt] = acc;
    }

    const float* brow = bias_eff + ((size_t)bh * Nn + i_glob) * Nn;
    const unsigned int* mrow = (const unsigned int*)(knn + ((size_t)(b * Nn + i_glob)) * Nn);
    float mx = -1e30f;
#pragma unroll
    for (int jt = 0; jt < 16; jt++) {
        f32x4 bi = *(const f32x4*)(brow + jt * 16 + lg * 4);
        unsigned int mk = mrow[jt * 4 + lg];
#pragma unroll
        for (int r = 0; r < 4; r++) {
            float v = fmaf(s[jt][r], 0.125f, bi[r]);
            v = ((mk >> (8 * r)) & 0xff) ? v : -1e9f;
            s[jt][r] = v;
            mx = fmaxf(mx, v);
        }
    }
    mx = fmaxf(mx, __shfl_xor(mx, 16, 64));
    mx = fmaxf(mx, __shfl_xor(mx, 32, 64));
    float sum = 0.0f;
#pragma unroll
    for (int jt = 0; jt < 16; jt++)
#pragma unroll
        for (int r = 0; r < 4; r++) {
            float e = __builtin_amdgcn_exp2f((s[jt][r] - mx) * 1.44269504f);
            s[jt][r] = e;
            sum += e;
        }
    sum += __shfl_xor(sum, 16, 64);
    sum += __shfl_xor(sum, 32, 64);
    float inv = 1.0f / sum;

    float* arow = attn_out + ((size_t)bh * Nn + i_glob) * Nn;
#pragma unroll
    for (int jt = 0; jt < 16; jt++) {
        f32x4 o4;
#pragma unroll
        for (int r = 0; r < 4; r++) {
            float a = s[jt][r] * inv;
            s[jt][r] = a;
            o4[r] = a;
        }
        *(f32x4*)(arow + jt * 16 + lg * 4) = o4;
    }

    f32x4 o[4];
#pragma unroll
    for (int dt = 0; dt < 4; dt++) o[dt] = (f32x4){0.f, 0.f, 0.f, 0.f};
    for (int half = 0; half < 2; half++) {
#pragma unroll
        for (int jr = 0; jr < 8; jr++) {
            int jt = half * 8 + jr;
            __bf16 pb[4];
#pragma unroll
            for (int r = 0; r < 4; r++) pb[r] = (__bf16)s[jt][r];
            *(uint2*)&Plds[w][lr][jr * 16 + lg * 4] = *(uint2*)pb;
        }
#pragma unroll
        for (int kk = 0; kk < 4; kk++) {
            bf16x8 pfrag = *(const bf16x8*)&Plds[w][lr][kk * 32 + lg * 8];
#pragma unroll
            for (int dt = 0; dt < 4; dt++) {
                bf16x8 vfrag = *(const bf16x8*)&Vt[dt * 16 + lr][half * 128 + kk * 32 + lg * 8];
                o[dt] = MFMA16(vfrag, pfrag, o[dt]);
            }
        }
    }

    __bf16* hrow = houtb + ((size_t)(b * Nn + i_glob)) * Cn + h * HDn;
#pragma unroll
    for (int dt = 0; dt < 4; dt++) {
        __bf16 hb[4];
#pragma unroll
        for (int r = 0; r < 4; r++) hb[r] = (__bf16)o[dt][r];
        *(uint2*)(hrow + dt * 16 + lg * 4) = *(uint2*)hb;
    }
}

// ---------------- output projection + residual: MFMA ----------------
__global__ void __launch_bounds__(256) k_proj(const __bf16* __restrict__ houtb,
                                              const __bf16* __restrict__ wpT,
                                              const float* __restrict__ bp,
                                              const float* __restrict__ x,
                                              float* __restrict__ xout) {
    int ib = blockIdx.x, y = blockIdx.y;
    int tid = threadIdx.x;
    int w = tid >> 6, l = tid & 63, lr = l & 15, lg = l >> 4;
    const __bf16* arow = houtb + (size_t)(ib * 64 + w * 16 + lr) * Cn;

    f32x4 acc[4];
#pragma unroll
    for (int ot = 0; ot < 4; ot++) acc[ot] = (f32x4){0.f, 0.f, 0.f, 0.f};
#pragma unroll
    for (int kc = 0; kc < 8; kc++) {
        bf16x8 af = *(const bf16x8*)(arow + kc * 32 + lg * 8);
#pragma unroll
        for (int ot = 0; ot < 4; ot++) {
            bf16x8 bfr = *(const bf16x8*)(wpT + (size_t)(y * 64 + ot * 16 + lr) * Cn +
                                          kc * 32 + lg * 8);
            acc[ot] = MFMA16(af, bfr, acc[ot]);
        }
    }
#pragma unroll
    for (int ot = 0; ot < 4; ot++) {
        int o = y * 64 + ot * 16 + lr;
        float bo = bp[o];
#pragma unroll
        for (int r = 0; r < 4; r++) {
            int ig = ib * 64 + w * 16 + lg * 4 + r;
            size_t idx = (size_t)ig * Cn + o;
            xout[idx] = x[idx] + bo + acc[ot][r];
        }
    }
}

extern "C" void kernel_launch(void* const* d_in, const int* in_sizes, int n_in,
                              void* d_out, int out_size, void* d_ws, size_t ws_size,
                              hipStream_t stream) {
    const float* x       = (const float*)d_in[0];
    const float* lang    = (const float*)d_in[1];
    const float* centers = (const float*)d_in[2];
    const float* corners = (const float*)d_in[3];
    const int*   obj     = (const int*)d_in[4];
    const float* ln_g    = (const float*)d_in[5];
    const float* ln_b    = (const float*)d_in[6];
    const float* W_qkv   = (const float*)d_in[7];
    const float* b_qkv   = (const float*)d_in[8];
    const float* W_proj  = (const float*)d_in[9];
    const float* b_proj  = (const float*)d_in[10];
    const float* Wg1     = (const float*)d_in[11];
    const float* bg1     = (const float*)d_in[12];
    const float* Wg2     = (const float*)d_in[13];
    const float* bg2     = (const float*)d_in[14];
    const float* Wt1     = (const float*)d_in[15];
    const float* bt1     = (const float*)d_in[16];
    const float* Wt2     = (const float*)d_in[17];
    const float* bt2     = (const float*)d_in[18];
    const float* alpha   = (const float*)d_in[19];

    float* out = (float*)d_out;
    float* xout     = out;                 // BL*N*C
    float* attn     = out + 1048576;       // BL*H*N*N
    float* bias_eff = out + 5242880;       // BL*H*N*N

    __bf16* xnb   = (__bf16*)d_ws;              // 1,048,576 bf16
    __bf16* qkvb  = xnb + 1048576;              // 3 x 1,048,576 bf16 (q,k,v)
    __bf16* houtb = qkvb + 3145728;             // 1,048,576 bf16
    __bf16* wqT   = houtb + 1048576;            // 196,608 bf16
    __bf16* wpT   = wqT + 196608;               // 65,536 bf16
    float*  sizes = (float*)(wpT + 65536);      // 12,288 f32
    float*  headw = sizes + 12288;              // 64 f32
    unsigned char* knn = (unsigned char*)(headw + 64);  // 1 MiB

    k_prep<<<8288, 256, 0, stream>>>(x, ln_g, ln_b, xnb, centers, obj, knn, corners, sizes,
                                     lang, Wt1, bt1, Wt2, bt2, headw, W_qkv, wqT, W_proj, wpT);
    k_heavy<<<4864, 256, 0, stream>>>(centers, sizes, Wg1, bg1, Wg2, bg2, headw, alpha,
                                      bias_eff, xnb, wqT, b_qkv, qkvb);
    k_attn<<<256, 256, 0, stream>>>(qkvb, bias_eff, knn, attn, houtb);
    k_proj<<<dim3(64, 4), 256, 0, stream>>>(houtb, wpT, b_proj, x, xout);
}